// Round 1
// baseline (5373.407 us; speedup 1.0000x reference)
//
#include <hip/hip_runtime.h>
#include <math.h>

namespace {
constexpr int KK = 24, BB = 128, CC = 128;

constexpr long long H2N   = (long long)KK * BB * CC * 81;
constexpr long long H3N   = (long long)KK * BB * CC * 49;
constexpr long long POOLN = (long long)BB * KK * 23;
constexpr long long TTN   = (long long)BB * KK * 1600;
constexpr long long BKN   = (long long)BB * KK;

constexpr long long WS_H2   = 0;
constexpr long long WS_H3   = WS_H2 + H2N;
constexpr long long WS_POOL = WS_H3 + H3N;
constexpr long long WS_TT   = WS_POOL + POOLN;
constexpr long long WS_SMAX = WS_TT + TTN;
constexpr long long WS_SDEN = WS_SMAX + BKN;
constexpr long long WS_DM   = WS_SDEN + BKN;
constexpr long long WS_PART = WS_DM + BKN;

constexpr long long OFF_OCAE = 1;
constexpr long long OFF_XM   = OFF_OCAE + (long long)BB * KK * 144;  // 442369
constexpr long long OFF_DM   = OFF_XM + (long long)BB * KK * 6;      // 460801
}

// ---------------- fused conv1 (1->128, 3x3 s2) + conv2 (128->128, 3x3 s2) ----------------
// one block per (k,b). h1 (128x19x19) is computed on the fly in ci-chunks of 8.
__global__ __launch_bounds__(256) void k_conv12(
    const float* __restrict__ x, const float* __restrict__ W1, const float* __restrict__ b1,
    const float* __restrict__ W2, const float* __restrict__ b2, float* __restrict__ h2)
{
  const int kb = blockIdx.x;
  const int k = kb / BB;
  const int b = kb - k * BB;
  const int t = threadIdx.x;

  __shared__ __align__(16) float xs[1600];
  __shared__ float w1s[1152];
  __shared__ float b1s[128];
  __shared__ float h1s[8 * 361 + 64];
  __shared__ __align__(16) float w2s[72 * 132];

  for (int i = t; i < 400; i += 256)
    ((float4*)xs)[i] = ((const float4*)(x + (size_t)b * 1600))[i];
  for (int i = t; i < 1152; i += 256) w1s[i] = W1[k * 1152 + i];
  if (t < 128) b1s[t] = b1[k * 128 + t];
  __syncthreads();

  const int g = t & 31;   // co group: co = 4g..4g+3
  const int q = t >> 5;   // position group: p = q + 8*i

  float acc0[11], acc1[11], acc2[11], acc3[11];
  #pragma unroll
  for (int i = 0; i < 11; ++i) { acc0[i] = 0.f; acc1[i] = 0.f; acc2[i] = 0.f; acc3[i] = 0.f; }

  int base[11];
  #pragma unroll
  for (int i = 0; i < 11; ++i) {
    const int p = q + 8 * i;
    const int py = p / 9, px = p - py * 9;
    base[i] = 38 * py + 2 * px;          // (2*py)*19 + 2*px
  }

  for (int ch = 0; ch < 16; ++ch) {
    const int ci0 = ch * 8;
    // stage W2 chunk transposed: lds[r][co], r = ci_local*9 + j
    for (int f = t; f < 9216; f += 256) {
      const int co = f / 72;
      const int r  = f - co * 72;
      w2s[r * 132 + co] = W2[(size_t)(k * 128 + co) * 1152 + ci0 * 9 + r];
    }
    // compute h1 chunk (8 channels of 19x19) from x
    for (int e = t; e < 2888; e += 256) {
      const int ci = e / 361;
      const int pp = e - ci * 361;
      const int oy = pp / 19;
      const int ox = pp - oy * 19;
      const float* wp = &w1s[(ci0 + ci) * 9];
      const float* xp = &xs[oy * 80 + ox * 2];
      float v = b1s[ci0 + ci];
      #pragma unroll
      for (int dy = 0; dy < 3; ++dy)
        #pragma unroll
        for (int dx = 0; dx < 3; ++dx)
          v = fmaf(wp[dy * 3 + dx], xp[dy * 40 + dx], v);
      h1s[e] = fmaxf(v, 0.0f);
    }
    __syncthreads();
    // MAC
    #pragma unroll
    for (int ci = 0; ci < 8; ++ci) {
      const int hb = ci * 361;
      #pragma unroll
      for (int j = 0; j < 9; ++j) {
        const float4 wv = *reinterpret_cast<const float4*>(&w2s[(ci * 9 + j) * 132 + 4 * g]);
        const int off = (j / 3) * 19 + (j - (j / 3) * 3);
        #pragma unroll
        for (int i = 0; i < 11; ++i) {
          const float hv = h1s[hb + base[i] + off];
          acc0[i] = fmaf(wv.x, hv, acc0[i]);
          acc1[i] = fmaf(wv.y, hv, acc1[i]);
          acc2[i] = fmaf(wv.z, hv, acc2[i]);
          acc3[i] = fmaf(wv.w, hv, acc3[i]);
        }
      }
    }
    __syncthreads();
  }

  const size_t ob = (size_t)(k * BB + b) * CC * 81;
  #pragma unroll
  for (int c = 0; c < 4; ++c) {
    const int co = 4 * g + c;
    const float bias = b2[k * 128 + co];
    const float* a = (c == 0) ? acc0 : (c == 1) ? acc1 : (c == 2) ? acc2 : acc3;
    #pragma unroll
    for (int i = 0; i < 11; ++i) {
      const int p = q + 8 * i;
      if (p < 81) h2[ob + (size_t)co * 81 + p] = fmaxf(a[i] + bias, 0.0f);
    }
  }
}

// ---------------- conv3 (128->128, 3x3 s1, 9->7) ----------------
__global__ __launch_bounds__(256) void k_conv3(
    const float* __restrict__ h2, const float* __restrict__ W3, const float* __restrict__ b3,
    float* __restrict__ h3)
{
  const int kb = blockIdx.x;
  const int k = kb / BB;
  const int b = kb - k * BB;
  const int t = threadIdx.x;

  __shared__ __align__(16) float h2s[128 * 81 + 32];
  __shared__ __align__(16) float w3s[72 * 132];

  const size_t ib = (size_t)(k * BB + b) * CC * 81;
  for (int i = t; i < 2592; i += 256)
    ((float4*)h2s)[i] = ((const float4*)(h2 + ib))[i];

  const int g = t & 31;
  const int q = t >> 5;

  float acc0[7], acc1[7], acc2[7], acc3[7];
  #pragma unroll
  for (int i = 0; i < 7; ++i) { acc0[i] = 0.f; acc1[i] = 0.f; acc2[i] = 0.f; acc3[i] = 0.f; }

  int base[7];
  #pragma unroll
  for (int i = 0; i < 7; ++i) {
    const int p = q + 8 * i;
    const int py = p / 7, px = p - py * 7;
    base[i] = py * 9 + px;
  }

  for (int ch = 0; ch < 16; ++ch) {
    const int ci0 = ch * 8;
    for (int f = t; f < 9216; f += 256) {
      const int co = f / 72;
      const int r  = f - co * 72;
      w3s[r * 132 + co] = W3[(size_t)(k * 128 + co) * 1152 + ci0 * 9 + r];
    }
    __syncthreads();
    #pragma unroll
    for (int ci = 0; ci < 8; ++ci) {
      const int hb = (ci0 + ci) * 81;
      #pragma unroll
      for (int j = 0; j < 9; ++j) {
        const float4 wv = *reinterpret_cast<const float4*>(&w3s[(ci * 9 + j) * 132 + 4 * g]);
        const int off = (j / 3) * 9 + (j - (j / 3) * 3);
        #pragma unroll
        for (int i = 0; i < 7; ++i) {
          const float hv = h2s[hb + base[i] + off];
          acc0[i] = fmaf(wv.x, hv, acc0[i]);
          acc1[i] = fmaf(wv.y, hv, acc1[i]);
          acc2[i] = fmaf(wv.z, hv, acc2[i]);
          acc3[i] = fmaf(wv.w, hv, acc3[i]);
        }
      }
    }
    __syncthreads();
  }

  const size_t ob = (size_t)(k * BB + b) * CC * 49;
  #pragma unroll
  for (int c = 0; c < 4; ++c) {
    const int co = 4 * g + c;
    const float bias = b3[k * 128 + co];
    const float* a = (c == 0) ? acc0 : (c == 1) ? acc1 : (c == 2) ? acc2 : acc3;
    #pragma unroll
    for (int i = 0; i < 7; ++i) {
      const int p = q + 8 * i;
      if (p < 49) h3[ob + (size_t)co * 49 + p] = fmaxf(a[i] + bias, 0.0f);
    }
  }
}

// ---------------- conv4 (7->5) + conv5 (1x1,128->24) + att softmax + pooling ----------------
__global__ __launch_bounds__(256) void k_conv45(
    const float* __restrict__ h3, const float* __restrict__ W4, const float* __restrict__ b4,
    const float* __restrict__ W5, const float* __restrict__ b5, float* __restrict__ pooled)
{
  const int kb = blockIdx.x;
  const int k = kb / BB;
  const int b = kb - k * BB;
  const int t = threadIdx.x;

  __shared__ __align__(16) float h3s[128 * 49 + 32];
  __shared__ __align__(16) float w4s[72 * 132];   // reused for W5 (3072 floats)
  __shared__ float h4s[128 * 25];
  __shared__ float outs_s[600];
  __shared__ float att_s[25];
  __shared__ float b5s[24];

  const size_t ib = (size_t)(k * BB + b) * CC * 49;
  for (int i = t; i < 1568; i += 256)
    ((float4*)h3s)[i] = ((const float4*)(h3 + ib))[i];

  const int g = t & 31;
  const int q = t >> 5;

  float acc0[4], acc1[4], acc2[4], acc3[4];
  #pragma unroll
  for (int i = 0; i < 4; ++i) { acc0[i] = 0.f; acc1[i] = 0.f; acc2[i] = 0.f; acc3[i] = 0.f; }

  int base[4];
  #pragma unroll
  for (int i = 0; i < 4; ++i) {
    const int p = q + 8 * i;
    const int py = p / 5, px = p - py * 5;
    base[i] = py * 7 + px;
  }

  for (int ch = 0; ch < 16; ++ch) {
    const int ci0 = ch * 8;
    for (int f = t; f < 9216; f += 256) {
      const int co = f / 72;
      const int r  = f - co * 72;
      w4s[r * 132 + co] = W4[(size_t)(k * 128 + co) * 1152 + ci0 * 9 + r];
    }
    __syncthreads();
    #pragma unroll
    for (int ci = 0; ci < 8; ++ci) {
      const int hb = (ci0 + ci) * 49;
      #pragma unroll
      for (int j = 0; j < 9; ++j) {
        const float4 wv = *reinterpret_cast<const float4*>(&w4s[(ci * 9 + j) * 132 + 4 * g]);
        const int off = (j / 3) * 7 + (j - (j / 3) * 3);
        #pragma unroll
        for (int i = 0; i < 4; ++i) {
          const float hv = h3s[hb + base[i] + off];
          acc0[i] = fmaf(wv.x, hv, acc0[i]);
          acc1[i] = fmaf(wv.y, hv, acc1[i]);
          acc2[i] = fmaf(wv.z, hv, acc2[i]);
          acc3[i] = fmaf(wv.w, hv, acc3[i]);
        }
      }
    }
    __syncthreads();
  }

  // h4 -> LDS (with bias+relu)
  #pragma unroll
  for (int c = 0; c < 4; ++c) {
    const int co = 4 * g + c;
    const float bias = b4[k * 128 + co];
    const float* a = (c == 0) ? acc0 : (c == 1) ? acc1 : (c == 2) ? acc2 : acc3;
    #pragma unroll
    for (int i = 0; i < 4; ++i) {
      const int p = q + 8 * i;
      if (p < 25) h4s[co * 25 + p] = fmaxf(a[i] + bias, 0.0f);
    }
  }
  // stage W5 into w4s area (safe: last MAC sync already passed)
  for (int i = t; i < 3072; i += 256) w4s[i] = W5[k * 3072 + i];
  if (t < 24) b5s[t] = b5[k * 24 + t];
  __syncthreads();

  // conv5: outs[fm][p], fm<24, p<25
  for (int o = t; o < 600; o += 256) {
    const int fm = o / 25;
    const int p  = o - fm * 25;
    float v = b5s[fm];
    const float* wp = &w4s[fm * 128];
    #pragma unroll 8
    for (int ci = 0; ci < 128; ++ci) v = fmaf(wp[ci], h4s[ci * 25 + p], v);
    outs_s[o] = v;
  }
  __syncthreads();

  // softmax over the 25 att values (fm==23)
  if (t < 64) {
    float v = (t < 25) ? outs_s[575 + t] : -1e30f;
    #pragma unroll
    for (int off = 32; off; off >>= 1) v = fmaxf(v, __shfl_xor(v, off));
    const float m = v;
    float e = (t < 25) ? expf(outs_s[575 + t] - m) : 0.0f;
    float s = e;
    #pragma unroll
    for (int off = 32; off; off >>= 1) s += __shfl_xor(s, off);
    if (t < 25) att_s[t] = e / s;
  }
  __syncthreads();

  if (t < 23) {
    float v = 0.f;
    #pragma unroll
    for (int p = 0; p < 25; ++p) v = fmaf(outs_s[t * 25 + p], att_s[p], v);
    pooled[(size_t)(b * KK + k) * 23 + t] = v;
  }
}

// ---------------- pose -> warp templates -> softmax stats; write ocae/x_m/d_m ----------------
__device__ inline float tapf(const float* tm, int yi, int xi) {
  const bool ok = (xi >= 0) & (xi < 11) & (yi >= 0) & (yi < 11);
  const int yc = min(max(yi, 0), 10), xc = min(max(xi, 0), 10);
  const float v = tm[yc * 11 + xc];
  return ok ? v : 0.0f;
}

__global__ __launch_bounds__(256) void k_pose_warp(
    const float* __restrict__ pooled, const float* __restrict__ noise,
    const float* __restrict__ templates, float* __restrict__ out,
    float* __restrict__ tt, float* __restrict__ smax, float* __restrict__ sden,
    float* __restrict__ dmw)
{
  const int bk = blockIdx.x;
  const int b = bk / KK;
  const int k = bk - b * KK;
  const int t = threadIdx.x;

  __shared__ float ps[23];
  __shared__ float tm[121];
  __shared__ float red[4];

  if (t < 23) ps[t] = pooled[(size_t)(b * KK + k) * 23 + t];
  for (int i = t; i < 121; i += 256) tm[i] = templates[k * 121 + i];
  __syncthreads();

  float xm[6];
  #pragma unroll
  for (int j = 0; j < 6; ++j) xm[j] = fmaxf(ps[j], 0.0f);
  const float dl = ps[6] + noise[b * KK + k];
  const float dm = 1.0f / (1.0f + expf(-dl));

  const size_t obase = OFF_OCAE + (size_t)(b * KK + k) * 144;
  if (t < 144) {
    float v;
    if (t == 0)       v = dm;
    else if (t < 7)   v = xm[t - 1];
    else if (t < 128) v = tm[t - 7];
    else              v = fmaxf(ps[7 + (t - 128)], 0.0f);
    out[obase + t] = v;
  }
  if (t < 6) out[OFF_XM + (size_t)(b * KK + k) * 6 + t] = xm[t];
  if (t == 0) out[OFF_DM + (b * KK + k)] = dm;

  // inverse affine
  const float D2R = 0.017453292519943295f;
  const float ang = xm[0] * D2R;
  const float tx = xm[1], ty = xm[2];
  const float sc = xm[3] + 1e-6f;
  const float sxr = xm[4] * D2R, syr = xm[5] * D2R;
  const float cas = cosf(ang - syr), sas = sinf(ang - syr);
  const float csy = cosf(syr), tsx = tanf(sxr);
  const float a_ = cas / csy;
  const float b_ = -cas * tsx / csy - sinf(ang);
  const float c_ = sas / csy;
  const float d_ = -sas * tsx / csy + cosf(ang);
  const float m00 = d_ / sc, m01 = -b_ / sc, m10 = -c_ / sc, m11 = a_ / sc;
  const float m02 = m00 * (-5.0f - tx) + m01 * (-5.0f - ty) + 5.0f;
  const float m12 = m10 * (-5.0f - tx) + m11 * (-5.0f - ty) + 5.0f;

  const float S = 0.275f;  // TS/W = 11/40
  float ttv[7];
  float lmax = -1e30f;
  #pragma unroll
  for (int i = 0; i < 7; ++i) {
    const int pix = t + 256 * i;
    float val = 0.0f;
    if (pix < 1600) {
      const int py = pix / 40, px = pix - 40 * py;
      const float u = (px + 0.5f) * S - 0.5f;
      const float v = (py + 0.5f) * S - 0.5f;
      const float sx = m00 * u + m01 * v + m02;
      const float sy = m10 * u + m11 * v + m12;
      const float x0 = floorf(sx), y0 = floorf(sy);
      const float wx = sx - x0, wy = sy - y0;
      const int xi = (int)x0, yi = (int)y0;
      const float v00 = tapf(tm, yi, xi);
      const float v01 = tapf(tm, yi, xi + 1);
      const float v10 = tapf(tm, yi + 1, xi);
      const float v11 = tapf(tm, yi + 1, xi + 1);
      val = (v00 * (1.0f - wx) + v01 * wx) * (1.0f - wy) + (v10 * (1.0f - wx) + v11 * wx) * wy;
      tt[(size_t)(b * KK + k) * 1600 + pix] = val;
      lmax = fmaxf(lmax, dm * val);
    }
    ttv[i] = val;
  }

  #pragma unroll
  for (int off = 32; off; off >>= 1) lmax = fmaxf(lmax, __shfl_xor(lmax, off));
  if ((t & 63) == 0) red[t >> 6] = lmax;
  __syncthreads();
  const float m = fmaxf(fmaxf(red[0], red[1]), fmaxf(red[2], red[3]));
  float ls = 0.0f;
  #pragma unroll
  for (int i = 0; i < 7; ++i)
    if (t + 256 * i < 1600) ls += expf(fmaf(dm, ttv[i], -m));
  #pragma unroll
  for (int off = 32; off; off >>= 1) ls += __shfl_xor(ls, off);
  __syncthreads();
  if ((t & 63) == 0) red[t >> 6] = ls;
  __syncthreads();
  if (t == 0) {
    smax[b * KK + k] = m;
    sden[b * KK + k] = red[0] + red[1] + red[2] + red[3];
    dmw[b * KK + k] = dm;
  }
}

// ---------------- per-pixel mixture + log; partial sums ----------------
__global__ __launch_bounds__(256) void k_ll(
    const float* __restrict__ x, const float* __restrict__ tt,
    const float* __restrict__ smax, const float* __restrict__ sden,
    const float* __restrict__ dmw, float* __restrict__ part)
{
  const int b = blockIdx.x >> 2;
  const int chunk = blockIdx.x & 3;
  const int t = threadIdx.x;

  __shared__ __align__(16) float xs[1600];
  __shared__ float kd[24], km[24], ki[24];
  __shared__ float red[4], red2[4];

  for (int i = t; i < 400; i += 256)
    ((float4*)xs)[i] = ((const float4*)(x + (size_t)b * 1600))[i];
  if (t < 24) {
    kd[t] = dmw[b * 24 + t];
    km[t] = smax[b * 24 + t];
    ki[t] = 1.0f / sden[b * 24 + t];
  }
  __syncthreads();

  // std over full image (ddof=1)
  float s1 = 0.f, s2 = 0.f;
  for (int i = t; i < 1600; i += 256) { const float v = xs[i]; s1 += v; s2 = fmaf(v, v, s2); }
  #pragma unroll
  for (int off = 32; off; off >>= 1) { s1 += __shfl_xor(s1, off); s2 += __shfl_xor(s2, off); }
  if ((t & 63) == 0) { red[t >> 6] = s1; red2[t >> 6] = s2; }
  __syncthreads();
  s1 = red[0] + red[1] + red[2] + red[3];
  s2 = red2[0] + red2[1] + red2[2] + red2[3];
  const float var = (s2 - s1 * s1 * (1.0f / 1600.0f)) * (1.0f / 1599.0f);
  const float stdv = sqrtf(var);
  const float mult = 1.0f / sqrtf(stdv * 6.283185307179586f);
  const float pmul = -1.0f / (2.0f * stdv * stdv);

  const int p0 = chunk * 400;
  float ll = 0.0f;
  for (int ii = t; ii < 400; ii += 256) {
    const int pix = p0 + ii;
    const float xv = xs[pix];
    float s = 0.0f;
    #pragma unroll 6
    for (int kk2 = 0; kk2 < 24; ++kk2) {
      const float tv = tt[(size_t)(b * 24 + kk2) * 1600 + pix];
      const float dxv = xv - tv;
      s += expf(fmaf(dxv * dxv, pmul, fmaf(kd[kk2], tv, -km[kk2]))) * ki[kk2];
    }
    ll += logf(mult * s);
  }
  #pragma unroll
  for (int off = 32; off; off >>= 1) ll += __shfl_xor(ll, off);
  __syncthreads();
  if ((t & 63) == 0) red[t >> 6] = ll;
  __syncthreads();
  if (t == 0) part[blockIdx.x] = red[0] + red[1] + red[2] + red[3];
}

__global__ void k_final(const float* __restrict__ part, float* __restrict__ out)
{
  const int t = threadIdx.x;  // 256
  float v = part[t] + part[t + 256];
  #pragma unroll
  for (int off = 32; off; off >>= 1) v += __shfl_xor(v, off);
  __shared__ float red[4];
  if ((t & 63) == 0) red[t >> 6] = v;
  __syncthreads();
  if (t == 0) out[0] = (red[0] + red[1] + red[2] + red[3]) * (1.0f / 128.0f);
}

extern "C" void kernel_launch(void* const* d_in, const int* in_sizes, int n_in,
                              void* d_out, int out_size, void* d_ws, size_t ws_size,
                              hipStream_t stream)
{
  const float* x     = (const float*)d_in[0];
  const float* noise = (const float*)d_in[1];
  const float* W1    = (const float*)d_in[2];
  const float* b1    = (const float*)d_in[3];
  const float* W2    = (const float*)d_in[4];
  const float* b2    = (const float*)d_in[5];
  const float* W3    = (const float*)d_in[6];
  const float* b3    = (const float*)d_in[7];
  const float* W4    = (const float*)d_in[8];
  const float* b4    = (const float*)d_in[9];
  const float* W5    = (const float*)d_in[10];
  const float* b5    = (const float*)d_in[11];
  const float* tmpl  = (const float*)d_in[12];
  float* out = (float*)d_out;
  float* ws  = (float*)d_ws;

  k_conv12<<<KK * BB, 256, 0, stream>>>(x, W1, b1, W2, b2, ws + WS_H2);
  k_conv3 <<<KK * BB, 256, 0, stream>>>(ws + WS_H2, W3, b3, ws + WS_H3);
  k_conv45<<<KK * BB, 256, 0, stream>>>(ws + WS_H3, W4, b4, W5, b5, ws + WS_POOL);
  k_pose_warp<<<BB * KK, 256, 0, stream>>>(ws + WS_POOL, noise, tmpl, out,
                                           ws + WS_TT, ws + WS_SMAX, ws + WS_SDEN, ws + WS_DM);
  k_ll<<<BB * 4, 256, 0, stream>>>(x, ws + WS_TT, ws + WS_SMAX, ws + WS_SDEN, ws + WS_DM,
                                   ws + WS_PART);
  k_final<<<1, 256, 0, stream>>>(ws + WS_PART, out);
}

// Round 3
// 2192.075 us; speedup vs baseline: 2.4513x; 2.4513x over previous
//
#include <hip/hip_runtime.h>
#include <math.h>

typedef __attribute__((ext_vector_type(8))) short bf16x8;
typedef __attribute__((ext_vector_type(4))) float f32x4;
typedef unsigned int uint32;
typedef unsigned short ushort;

namespace {
constexpr int KK = 24, BB = 128;

// ---- workspace byte offsets ----
constexpr size_t SZ_WB   = (size_t)24 * 128 * 1152 * 2;          // 7,077,888
constexpr size_t OFF_WB2 = 0;
constexpr size_t OFF_WB3 = OFF_WB2 + SZ_WB;
constexpr size_t OFF_WB4 = OFF_WB3 + SZ_WB;
constexpr size_t OFF_H2B = OFF_WB4 + SZ_WB;                       // bf16 h2: 24*128*128*81
constexpr size_t SZ_H2B  = (size_t)24 * 128 * 128 * 81 * 2;
constexpr size_t OFF_H3B = OFF_H2B + SZ_H2B;                      // bf16 h3: 24*128*128*49
constexpr size_t SZ_H3B  = (size_t)24 * 128 * 128 * 49 * 2;
constexpr size_t OFF_POOL = OFF_H3B + SZ_H3B;                     // f32 [b*24+k]*23
constexpr size_t SZ_POOL  = (size_t)128 * 24 * 23 * 4;
constexpr size_t OFF_TT   = OFF_POOL + SZ_POOL;                   // f32 [b*24+k]*1600
constexpr size_t SZ_TT    = (size_t)128 * 24 * 1600 * 4;
constexpr size_t OFF_SMAX = OFF_TT + SZ_TT;
constexpr size_t OFF_SDEN = OFF_SMAX + 12288;
constexpr size_t OFF_DM   = OFF_SDEN + 12288;
constexpr size_t OFF_PART = OFF_DM + 12288;

// ---- output offsets (floats) ----
constexpr long long O_OCAE = 1;
constexpr long long O_XM   = O_OCAE + (long long)BB * KK * 144;
constexpr long long O_DM   = O_XM + (long long)BB * KK * 6;
}

__device__ inline ushort f2bf(float f) {
  uint32 u = __builtin_bit_cast(uint32, f);
  u += 0x7fffu + ((u >> 16) & 1u);
  return (ushort)(u >> 16);
}

// ---------------- f32 -> bf16 weight conversion ----------------
__global__ __launch_bounds__(256) void k_cvt(const float* __restrict__ src,
                                             ushort* __restrict__ dst) {
  const int i = blockIdx.x * 256 + threadIdx.x;   // grid sized exactly n/4
  const float4 v = ((const float4*)src)[i];
  ushort4 o;
  o.x = f2bf(v.x); o.y = f2bf(v.y); o.z = f2bf(v.z); o.w = f2bf(v.w);
  ((ushort4*)dst)[i] = o;
}

// ---------------- conv1(1->128,3x3,s2) fused + conv2(128->128,3x3,s2) via MFMA ----------------
// per (k,b) block. GEMM: [128 co] x [K=1152] x [N=81->96]
__global__ __launch_bounds__(256) void k_conv2m(
    const float* __restrict__ x, const float* __restrict__ W1, const float* __restrict__ b1,
    const ushort* __restrict__ W2b, const float* __restrict__ b2, ushort* __restrict__ h2b)
{
  const int kb = blockIdx.x;
  const int k = kb >> 7;
  const int b = kb & 127;
  const int t = threadIdx.x;

  __shared__ __align__(16) float xs[1600];
  __shared__ float w1s[1152];
  __shared__ float b1s[128], b2s[128];
  __shared__ ushort tbl[288];
  __shared__ __align__(16) ushort h1s[16 * 361];     // 11.5 KB (half-chunk of 16 ci)
  __shared__ __align__(16) ushort imc[96 * 296];     // 56.8 KB
  __shared__ __align__(16) ushort wld[128 * 296];    // 75.8 KB

  for (int i = t; i < 400; i += 256)
    ((float4*)xs)[i] = ((const float4*)(x + (size_t)b * 1600))[i];
  for (int i = t; i < 1152; i += 256) w1s[i] = W1[k * 1152 + i];
  if (t < 128) { b1s[t] = b1[k * 128 + t]; b2s[t] = b2[k * 128 + t]; }
  for (int i = t; i < 288; i += 256) {
    const int ci = i / 9, jj = i - 9 * ci;
    tbl[i] = (ushort)(ci * 361 + (jj / 3) * 19 + (jj - 3 * (jj / 3)));
  }

  const int w = t >> 6, lane = t & 63, r = lane & 15, s = lane >> 4;
  const int m0 = (w & 1) * 64;       // 4 M-tiles per wave
  const int n0 = (w >> 1) * 48;      // 3 N-tiles per wave
  f32x4 acc[4][3];
  #pragma unroll
  for (int mi = 0; mi < 4; ++mi)
    #pragma unroll
    for (int ni = 0; ni < 3; ++ni) acc[mi][ni] = (f32x4){0.f, 0.f, 0.f, 0.f};

  for (int c = 0; c < 4; ++c) {
    __syncthreads();   // protect wld/imc/h1s from previous chunk readers (and initial staging)
    // stage W chunk [128][288] -> wld[co*296 + kk]
    for (int f = t; f < 4608; f += 256) {
      const int co = f / 36, ko = f - 36 * co;
      const uint4 v = *(const uint4*)(W2b + (size_t)k * 147456 + co * 1152 + c * 288 + 8 * ko);
      *(uint4*)(wld + co * 296 + 8 * ko) = v;
    }
    #pragma unroll
    for (int h = 0; h < 2; ++h) {
      // conv1: compute h1 for ci in [32c+16h, +16)
      for (int e = t; e < 5776; e += 256) {
        const int ci = e / 361;
        const int pp = e - 361 * ci;
        const int oy = pp / 19, ox = pp - 19 * oy;
        const int cig = 32 * c + 16 * h + ci;
        const float* wp = &w1s[cig * 9];
        const float* xp = &xs[oy * 80 + ox * 2];
        float v = b1s[cig];
        #pragma unroll
        for (int dy = 0; dy < 3; ++dy)
          #pragma unroll
          for (int dx = 0; dx < 3; ++dx)
            v = fmaf(wp[dy * 3 + dx], xp[dy * 40 + dx], v);
        h1s[e] = f2bf(fmaxf(v, 0.0f));
      }
      __syncthreads();
      // im2col rows k in [144h, 144h+144)
      for (int f = t; f < 96 * 18; f += 256) {
        const int n = f / 18;
        const int ko = 18 * h + (f - 18 * (f / 18));
        const int py = n / 9, px = n - 9 * py;
        const int base = 38 * py + 2 * px - 5776 * h;
        const bool ok = n < 81;
        uint32 u[4];
        #pragma unroll
        for (int e2 = 0; e2 < 4; ++e2) {
          const int kk = 8 * ko + 2 * e2;
          const ushort v0 = ok ? h1s[tbl[kk] + base] : (ushort)0;
          const ushort v1 = ok ? h1s[tbl[kk + 1] + base] : (ushort)0;
          u[e2] = (uint32)v0 | ((uint32)v1 << 16);
        }
        *(uint4*)(imc + n * 296 + 8 * ko) = make_uint4(u[0], u[1], u[2], u[3]);
      }
      __syncthreads();
    }
    // MFMA: 9 K-steps of 32
    #pragma unroll
    for (int ks = 0; ks < 9; ++ks) {
      bf16x8 a[4], bf[3];
      #pragma unroll
      for (int mi = 0; mi < 4; ++mi)
        a[mi] = *(const bf16x8*)(wld + (m0 + 16 * mi + r) * 296 + 32 * ks + 8 * s);
      #pragma unroll
      for (int ni = 0; ni < 3; ++ni)
        bf[ni] = *(const bf16x8*)(imc + (n0 + 16 * ni + r) * 296 + 32 * ks + 8 * s);
      #pragma unroll
      for (int mi = 0; mi < 4; ++mi)
        #pragma unroll
        for (int ni = 0; ni < 3; ++ni)
          acc[mi][ni] = __builtin_amdgcn_mfma_f32_16x16x32_bf16(a[mi], bf[ni], acc[mi][ni], 0, 0, 0);
    }
  }
  // epilogue: C[row=co][col=p], row=(lane>>4)*4+reg, col=lane&15
  const size_t ob = (size_t)kb * (128 * 81);
  #pragma unroll
  for (int mi = 0; mi < 4; ++mi)
    #pragma unroll
    for (int ni = 0; ni < 3; ++ni) {
      const int p = n0 + 16 * ni + r;
      if (p < 81) {
        #pragma unroll
        for (int rg = 0; rg < 4; ++rg) {
          const int co = m0 + 16 * mi + 4 * s + rg;
          h2b[ob + co * 81 + p] = f2bf(fmaxf(acc[mi][ni][rg] + b2s[co], 0.0f));
        }
      }
    }
}

// ---------------- conv3 (128->128, 3x3 s1, 9->7) via MFMA ----------------
__global__ __launch_bounds__(256) void k_conv3m(
    const ushort* __restrict__ h2b, const ushort* __restrict__ W3b,
    const float* __restrict__ b3, ushort* __restrict__ h3b)
{
  const int kb = blockIdx.x;
  const int k = kb >> 7;
  const int t = threadIdx.x;

  __shared__ float b3s[128];
  __shared__ ushort tbl[288];
  __shared__ __align__(16) ushort hins[32 * 81];     // 5.2 KB
  __shared__ __align__(16) ushort imc[64 * 296];     // 37.9 KB
  __shared__ __align__(16) ushort wld[128 * 296];    // 75.8 KB

  if (t < 128) b3s[t] = b3[k * 128 + t];
  for (int i = t; i < 288; i += 256) {
    const int ci = i / 9, jj = i - 9 * ci;
    tbl[i] = (ushort)(ci * 81 + (jj / 3) * 9 + (jj - 3 * (jj / 3)));
  }

  const int w = t >> 6, lane = t & 63, r = lane & 15, s = lane >> 4;
  const int m0 = (w & 1) * 64;     // WM=4
  const int n0 = (w >> 1) * 32;    // WN=2
  f32x4 acc[4][2];
  #pragma unroll
  for (int mi = 0; mi < 4; ++mi)
    #pragma unroll
    for (int ni = 0; ni < 2; ++ni) acc[mi][ni] = (f32x4){0.f, 0.f, 0.f, 0.f};

  for (int c = 0; c < 4; ++c) {
    __syncthreads();
    for (int f = t; f < 4608; f += 256) {
      const int co = f / 36, ko = f - 36 * co;
      const uint4 v = *(const uint4*)(W3b + (size_t)k * 147456 + co * 1152 + c * 288 + 8 * ko);
      *(uint4*)(wld + co * 296 + 8 * ko) = v;
    }
    for (int f = t; f < 324; f += 256) {
      const uint4 v = *(const uint4*)(h2b + (size_t)kb * 10368 + 2592 * c + 8 * f);
      *(uint4*)(hins + 8 * f) = v;
    }
    __syncthreads();
    for (int f = t; f < 64 * 36; f += 256) {
      const int n = f / 36, ko = f - 36 * (f / 36);
      const int py = n / 7, px = n - 7 * py;
      const int base = 9 * py + px;
      const bool ok = n < 49;
      uint32 u[4];
      #pragma unroll
      for (int e2 = 0; e2 < 4; ++e2) {
        const int kk = 8 * ko + 2 * e2;
        const ushort v0 = ok ? hins[tbl[kk] + base] : (ushort)0;
        const ushort v1 = ok ? hins[tbl[kk + 1] + base] : (ushort)0;
        u[e2] = (uint32)v0 | ((uint32)v1 << 16);
      }
      *(uint4*)(imc + n * 296 + 8 * ko) = make_uint4(u[0], u[1], u[2], u[3]);
    }
    __syncthreads();
    #pragma unroll
    for (int ks = 0; ks < 9; ++ks) {
      bf16x8 a[4], bf[2];
      #pragma unroll
      for (int mi = 0; mi < 4; ++mi)
        a[mi] = *(const bf16x8*)(wld + (m0 + 16 * mi + r) * 296 + 32 * ks + 8 * s);
      #pragma unroll
      for (int ni = 0; ni < 2; ++ni)
        bf[ni] = *(const bf16x8*)(imc + (n0 + 16 * ni + r) * 296 + 32 * ks + 8 * s);
      #pragma unroll
      for (int mi = 0; mi < 4; ++mi)
        #pragma unroll
        for (int ni = 0; ni < 2; ++ni)
          acc[mi][ni] = __builtin_amdgcn_mfma_f32_16x16x32_bf16(a[mi], bf[ni], acc[mi][ni], 0, 0, 0);
    }
  }
  const size_t ob = (size_t)kb * (128 * 49);
  #pragma unroll
  for (int mi = 0; mi < 4; ++mi)
    #pragma unroll
    for (int ni = 0; ni < 2; ++ni) {
      const int p = n0 + 16 * ni + r;
      if (p < 49) {
        #pragma unroll
        for (int rg = 0; rg < 4; ++rg) {
          const int co = m0 + 16 * mi + 4 * s + rg;
          h3b[ob + co * 49 + p] = f2bf(fmaxf(acc[mi][ni][rg] + b3s[co], 0.0f));
        }
      }
    }
}

// ---------------- conv4 (7->5) MFMA + conv5 (1x1) + att softmax + pooling ----------------
__global__ __launch_bounds__(256) void k_conv45m(
    const ushort* __restrict__ h3b, const ushort* __restrict__ W4b, const float* __restrict__ b4,
    const float* __restrict__ W5, const float* __restrict__ b5, float* __restrict__ pooled)
{
  const int kb = blockIdx.x;
  const int k = kb >> 7;
  const int b = kb & 127;
  const int t = threadIdx.x;

  __shared__ float b4s[128];
  __shared__ ushort tbl[288];
  __shared__ __align__(16) ushort hins[32 * 49];
  __shared__ __align__(16) ushort imc[32 * 296];
  __shared__ __align__(16) ushort wld[128 * 296];
  __shared__ float h4s[128 * 26];
  __shared__ float w5s[3072];
  __shared__ float b5s[24];
  __shared__ float outs_s[600];
  __shared__ float att_s[25];

  if (t < 128) b4s[t] = b4[k * 128 + t];
  for (int i = t; i < 288; i += 256) {
    const int ci = i / 9, jj = i - 9 * ci;
    tbl[i] = (ushort)(ci * 49 + (jj / 3) * 7 + (jj - 3 * (jj / 3)));
  }
  for (int i = t; i < 3072; i += 256) w5s[i] = W5[k * 3072 + i];
  if (t < 24) b5s[t] = b5[k * 24 + t];

  const int w = t >> 6, lane = t & 63, r = lane & 15, s = lane >> 4;
  const int m0 = w * 32;   // WM=2, GN=1
  f32x4 acc[2][2];
  #pragma unroll
  for (int mi = 0; mi < 2; ++mi)
    #pragma unroll
    for (int ni = 0; ni < 2; ++ni) acc[mi][ni] = (f32x4){0.f, 0.f, 0.f, 0.f};

  for (int c = 0; c < 4; ++c) {
    __syncthreads();
    for (int f = t; f < 4608; f += 256) {
      const int co = f / 36, ko = f - 36 * co;
      const uint4 v = *(const uint4*)(W4b + (size_t)k * 147456 + co * 1152 + c * 288 + 8 * ko);
      *(uint4*)(wld + co * 296 + 8 * ko) = v;
    }
    for (int f = t; f < 196; f += 256) {
      const uint4 v = *(const uint4*)(h3b + (size_t)kb * 6272 + 1568 * c + 8 * f);
      *(uint4*)(hins + 8 * f) = v;
    }
    __syncthreads();
    for (int f = t; f < 32 * 36; f += 256) {
      const int n = f / 36, ko = f - 36 * (f / 36);
      const int py = n / 5, px = n - 5 * py;
      const int base = 7 * py + px;
      const bool ok = n < 25;
      uint32 u[4];
      #pragma unroll
      for (int e2 = 0; e2 < 4; ++e2) {
        const int kk = 8 * ko + 2 * e2;
        const ushort v0 = ok ? hins[tbl[kk] + base] : (ushort)0;
        const ushort v1 = ok ? hins[tbl[kk + 1] + base] : (ushort)0;
        u[e2] = (uint32)v0 | ((uint32)v1 << 16);
      }
      *(uint4*)(imc + n * 296 + 8 * ko) = make_uint4(u[0], u[1], u[2], u[3]);
    }
    __syncthreads();
    #pragma unroll
    for (int ks = 0; ks < 9; ++ks) {
      bf16x8 a[2], bf[2];
      #pragma unroll
      for (int mi = 0; mi < 2; ++mi)
        a[mi] = *(const bf16x8*)(wld + (m0 + 16 * mi + r) * 296 + 32 * ks + 8 * s);
      #pragma unroll
      for (int ni = 0; ni < 2; ++ni)
        bf[ni] = *(const bf16x8*)(imc + (16 * ni + r) * 296 + 32 * ks + 8 * s);
      #pragma unroll
      for (int mi = 0; mi < 2; ++mi)
        #pragma unroll
        for (int ni = 0; ni < 2; ++ni)
          acc[mi][ni] = __builtin_amdgcn_mfma_f32_16x16x32_bf16(a[mi], bf[ni], acc[mi][ni], 0, 0, 0);
    }
  }
  // h4 -> LDS f32 (bias + relu)
  #pragma unroll
  for (int mi = 0; mi < 2; ++mi)
    #pragma unroll
    for (int ni = 0; ni < 2; ++ni) {
      const int p = 16 * ni + r;
      if (p < 25) {
        #pragma unroll
        for (int rg = 0; rg < 4; ++rg) {
          const int co = m0 + 16 * mi + 4 * s + rg;
          h4s[co * 26 + p] = fmaxf(acc[mi][ni][rg] + b4s[co], 0.0f);
        }
      }
    }
  __syncthreads();

  // conv5: outs[fm][p]
  for (int o = t; o < 600; o += 256) {
    const int fm = o / 25;
    const int p = o - fm * 25;
    float v = b5s[fm];
    const float* wp = &w5s[fm * 128];
    #pragma unroll 8
    for (int ci = 0; ci < 128; ++ci) v = fmaf(wp[ci], h4s[ci * 26 + p], v);
    outs_s[o] = v;
  }
  __syncthreads();

  if (t < 64) {
    float v = (t < 25) ? outs_s[575 + t] : -1e30f;
    #pragma unroll
    for (int off = 32; off; off >>= 1) v = fmaxf(v, __shfl_xor(v, off));
    const float m = v;
    float e = (t < 25) ? expf(outs_s[575 + t] - m) : 0.0f;
    float ss = e;
    #pragma unroll
    for (int off = 32; off; off >>= 1) ss += __shfl_xor(ss, off);
    if (t < 25) att_s[t] = e / ss;
  }
  __syncthreads();

  if (t < 23) {
    float v = 0.f;
    #pragma unroll
    for (int p = 0; p < 25; ++p) v = fmaf(outs_s[t * 25 + p], att_s[p], v);
    pooled[(size_t)(b * KK + k) * 23 + t] = v;
  }
}

// ---------------- pose -> warp templates -> softmax stats ----------------
__device__ inline float tapf(const float* tm, int yi, int xi) {
  const bool ok = (xi >= 0) & (xi < 11) & (yi >= 0) & (yi < 11);
  const int yc = min(max(yi, 0), 10), xc = min(max(xi, 0), 10);
  const float v = tm[yc * 11 + xc];
  return ok ? v : 0.0f;
}

__global__ __launch_bounds__(256) void k_pose_warp(
    const float* __restrict__ pooled, const float* __restrict__ noise,
    const float* __restrict__ templates, float* __restrict__ out,
    float* __restrict__ tt, float* __restrict__ smax, float* __restrict__ sden,
    float* __restrict__ dmw)
{
  const int bk = blockIdx.x;
  const int b = bk / KK;
  const int k = bk - b * KK;
  const int t = threadIdx.x;

  __shared__ float ps[23];
  __shared__ float tm[121];
  __shared__ float red[4];

  if (t < 23) ps[t] = pooled[(size_t)(b * KK + k) * 23 + t];
  for (int i = t; i < 121; i += 256) tm[i] = templates[k * 121 + i];
  __syncthreads();

  float xm[6];
  #pragma unroll
  for (int j = 0; j < 6; ++j) xm[j] = fmaxf(ps[j], 0.0f);
  const float dl = ps[6] + noise[b * KK + k];
  const float dm = 1.0f / (1.0f + expf(-dl));

  const size_t obase = O_OCAE + (size_t)(b * KK + k) * 144;
  if (t < 144) {
    float v;
    if (t == 0)       v = dm;
    else if (t < 7)   v = xm[t - 1];
    else if (t < 128) v = tm[t - 7];
    else              v = fmaxf(ps[7 + (t - 128)], 0.0f);
    out[obase + t] = v;
  }
  if (t < 6) out[O_XM + (size_t)(b * KK + k) * 6 + t] = xm[t];
  if (t == 0) out[O_DM + (b * KK + k)] = dm;

  const float D2R = 0.017453292519943295f;
  const float ang = xm[0] * D2R;
  const float tx = xm[1], ty = xm[2];
  const float sc = xm[3] + 1e-6f;
  const float sxr = xm[4] * D2R, syr = xm[5] * D2R;
  const float cas = cosf(ang - syr), sas = sinf(ang - syr);
  const float csy = cosf(syr), tsx = tanf(sxr);
  const float a_ = cas / csy;
  const float b_ = -cas * tsx / csy - sinf(ang);
  const float c_ = sas / csy;
  const float d_ = -sas * tsx / csy + cosf(ang);
  const float m00 = d_ / sc, m01 = -b_ / sc, m10 = -c_ / sc, m11 = a_ / sc;
  const float m02 = m00 * (-5.0f - tx) + m01 * (-5.0f - ty) + 5.0f;
  const float m12 = m10 * (-5.0f - tx) + m11 * (-5.0f - ty) + 5.0f;

  const float S = 0.275f;
  float ttv[7];
  float lmax = -1e30f;
  #pragma unroll
  for (int i = 0; i < 7; ++i) {
    const int pix = t + 256 * i;
    float val = 0.0f;
    if (pix < 1600) {
      const int py = pix / 40, px = pix - 40 * py;
      const float u = (px + 0.5f) * S - 0.5f;
      const float v = (py + 0.5f) * S - 0.5f;
      const float sx = m00 * u + m01 * v + m02;
      const float sy = m10 * u + m11 * v + m12;
      const float x0 = floorf(sx), y0 = floorf(sy);
      const float wx = sx - x0, wy = sy - y0;
      const int xi = (int)x0, yi = (int)y0;
      const float v00 = tapf(tm, yi, xi);
      const float v01 = tapf(tm, yi, xi + 1);
      const float v10 = tapf(tm, yi + 1, xi);
      const float v11 = tapf(tm, yi + 1, xi + 1);
      val = (v00 * (1.0f - wx) + v01 * wx) * (1.0f - wy) + (v10 * (1.0f - wx) + v11 * wx) * wy;
      tt[(size_t)(b * KK + k) * 1600 + pix] = val;
      lmax = fmaxf(lmax, dm * val);
    }
    ttv[i] = val;
  }

  #pragma unroll
  for (int off = 32; off; off >>= 1) lmax = fmaxf(lmax, __shfl_xor(lmax, off));
  if ((t & 63) == 0) red[t >> 6] = lmax;
  __syncthreads();
  const float m = fmaxf(fmaxf(red[0], red[1]), fmaxf(red[2], red[3]));
  float ls = 0.0f;
  #pragma unroll
  for (int i = 0; i < 7; ++i)
    if (t + 256 * i < 1600) ls += expf(fmaf(dm, ttv[i], -m));
  #pragma unroll
  for (int off = 32; off; off >>= 1) ls += __shfl_xor(ls, off);
  __syncthreads();
  if ((t & 63) == 0) red[t >> 6] = ls;
  __syncthreads();
  if (t == 0) {
    smax[b * KK + k] = m;
    sden[b * KK + k] = red[0] + red[1] + red[2] + red[3];
    dmw[b * KK + k] = dm;
  }
}

// ---------------- per-pixel mixture + log; partial sums ----------------
__global__ __launch_bounds__(256) void k_ll(
    const float* __restrict__ x, const float* __restrict__ tt,
    const float* __restrict__ smax, const float* __restrict__ sden,
    const float* __restrict__ dmw, float* __restrict__ part)
{
  const int b = blockIdx.x >> 2;
  const int chunk = blockIdx.x & 3;
  const int t = threadIdx.x;

  __shared__ __align__(16) float xs[1600];
  __shared__ float kd[24], km[24], ki[24];
  __shared__ float red[4], red2[4];

  for (int i = t; i < 400; i += 256)
    ((float4*)xs)[i] = ((const float4*)(x + (size_t)b * 1600))[i];
  if (t < 24) {
    kd[t] = dmw[b * 24 + t];
    km[t] = smax[b * 24 + t];
    ki[t] = 1.0f / sden[b * 24 + t];
  }
  __syncthreads();

  float s1 = 0.f, s2 = 0.f;
  for (int i = t; i < 1600; i += 256) { const float v = xs[i]; s1 += v; s2 = fmaf(v, v, s2); }
  #pragma unroll
  for (int off = 32; off; off >>= 1) { s1 += __shfl_xor(s1, off); s2 += __shfl_xor(s2, off); }
  if ((t & 63) == 0) { red[t >> 6] = s1; red2[t >> 6] = s2; }
  __syncthreads();
  s1 = red[0] + red[1] + red[2] + red[3];
  s2 = red2[0] + red2[1] + red2[2] + red2[3];
  const float var = (s2 - s1 * s1 * (1.0f / 1600.0f)) * (1.0f / 1599.0f);
  const float stdv = sqrtf(var);
  const float mult = 1.0f / sqrtf(stdv * 6.283185307179586f);
  const float pmul = -1.0f / (2.0f * stdv * stdv);

  const int p0 = chunk * 400;
  float ll = 0.0f;
  for (int ii = t; ii < 400; ii += 256) {
    const int pix = p0 + ii;
    const float xv = xs[pix];
    float sum = 0.0f;
    #pragma unroll 6
    for (int kk2 = 0; kk2 < 24; ++kk2) {
      const float tv = tt[(size_t)(b * 24 + kk2) * 1600 + pix];
      const float dxv = xv - tv;
      sum += expf(fmaf(dxv * dxv, pmul, fmaf(kd[kk2], tv, -km[kk2]))) * ki[kk2];
    }
    ll += logf(mult * sum);
  }
  #pragma unroll
  for (int off = 32; off; off >>= 1) ll += __shfl_xor(ll, off);
  __syncthreads();
  if ((t & 63) == 0) red[t >> 6] = ll;
  __syncthreads();
  if (t == 0) part[blockIdx.x] = red[0] + red[1] + red[2] + red[3];
}

__global__ void k_final(const float* __restrict__ part, float* __restrict__ out)
{
  const int t = threadIdx.x;
  float v = part[t] + part[t + 256];
  #pragma unroll
  for (int off = 32; off; off >>= 1) v += __shfl_xor(v, off);
  __shared__ float red[4];
  if ((t & 63) == 0) red[t >> 6] = v;
  __syncthreads();
  if (t == 0) out[0] = (red[0] + red[1] + red[2] + red[3]) * (1.0f / 128.0f);
}

extern "C" void kernel_launch(void* const* d_in, const int* in_sizes, int n_in,
                              void* d_out, int out_size, void* d_ws, size_t ws_size,
                              hipStream_t stream)
{
  const float* x     = (const float*)d_in[0];
  const float* noise = (const float*)d_in[1];
  const float* W1    = (const float*)d_in[2];
  const float* b1    = (const float*)d_in[3];
  const float* W2    = (const float*)d_in[4];
  const float* b2    = (const float*)d_in[5];
  const float* W3    = (const float*)d_in[6];
  const float* b3    = (const float*)d_in[7];
  const float* W4    = (const float*)d_in[8];
  const float* b4    = (const float*)d_in[9];
  const float* W5    = (const float*)d_in[10];
  const float* b5    = (const float*)d_in[11];
  const float* tmpl  = (const float*)d_in[12];
  float* out = (float*)d_out;
  char* wsb = (char*)d_ws;

  ushort* W2b = (ushort*)(wsb + OFF_WB2);
  ushort* W3b = (ushort*)(wsb + OFF_WB3);
  ushort* W4b = (ushort*)(wsb + OFF_WB4);
  ushort* h2b = (ushort*)(wsb + OFF_H2B);
  ushort* h3b = (ushort*)(wsb + OFF_H3B);
  float* poolp = (float*)(wsb + OFF_POOL);
  float* ttp   = (float*)(wsb + OFF_TT);
  float* smaxp = (float*)(wsb + OFF_SMAX);
  float* sdenp = (float*)(wsb + OFF_SDEN);
  float* dmp   = (float*)(wsb + OFF_DM);
  float* partp = (float*)(wsb + OFF_PART);

  k_cvt<<<3456, 256, 0, stream>>>(W2, W2b);
  k_cvt<<<3456, 256, 0, stream>>>(W3, W3b);
  k_cvt<<<3456, 256, 0, stream>>>(W4, W4b);
  k_conv2m<<<KK * BB, 256, 0, stream>>>(x, W1, b1, W2b, b2, h2b);
  k_conv3m<<<KK * BB, 256, 0, stream>>>(h2b, W3b, b3, h3b);
  k_conv45m<<<KK * BB, 256, 0, stream>>>(h3b, W4b, b4, W5, b5, poolp);
  k_pose_warp<<<BB * KK, 256, 0, stream>>>(poolp, noise, tmpl, out, ttp, smaxp, sdenp, dmp);
  k_ll<<<BB * 4, 256, 0, stream>>>(x, ttp, smaxp, sdenp, dmp, partp);
  k_final<<<1, 256, 0, stream>>>(partp, out);
}

// Round 4
// 412.381 us; speedup vs baseline: 13.0302x; 5.3156x over previous
//
#include <hip/hip_runtime.h>
#include <math.h>

typedef __attribute__((ext_vector_type(8))) short bf16x8;
typedef __attribute__((ext_vector_type(4))) short bf16x4;
typedef __attribute__((ext_vector_type(4))) float f32x4;
typedef unsigned int uint32;
typedef unsigned short ushort;

namespace {
constexpr int KK = 24, BB = 128;

// ---- workspace byte offsets ----
constexpr size_t SZ_W1P = (size_t)24 * 128 * 32 * 2;              // 196,608
constexpr size_t SZ_WB  = (size_t)24 * 128 * 1152 * 2;            // 7,077,888
constexpr size_t OFF_W1P = 0;
constexpr size_t OFF_WB2 = OFF_W1P + SZ_W1P;
constexpr size_t OFF_WB3 = OFF_WB2 + SZ_WB;
constexpr size_t OFF_WB4 = OFF_WB3 + SZ_WB;
constexpr size_t OFF_H2T = OFF_WB4 + SZ_WB;                       // bf16 [kb][81][128]
constexpr size_t SZ_H2T  = (size_t)3072 * 81 * 128 * 2;
constexpr size_t OFF_H3T = OFF_H2T + SZ_H2T;                      // bf16 [kb][49][128]
constexpr size_t SZ_H3T  = (size_t)3072 * 49 * 128 * 2;
constexpr size_t OFF_POOL = OFF_H3T + SZ_H3T;
constexpr size_t SZ_POOL  = (size_t)128 * 24 * 23 * 4;
constexpr size_t OFF_TT   = OFF_POOL + SZ_POOL;
constexpr size_t SZ_TT    = (size_t)128 * 24 * 1600 * 4;
constexpr size_t OFF_SMAX = OFF_TT + SZ_TT;
constexpr size_t OFF_SDEN = OFF_SMAX + 12288;
constexpr size_t OFF_DM   = OFF_SDEN + 12288;
constexpr size_t OFF_PART = OFF_DM + 12288;

// ---- output offsets (floats) ----
constexpr long long O_OCAE = 1;
constexpr long long O_XM   = O_OCAE + (long long)BB * KK * 144;
constexpr long long O_DM   = O_XM + (long long)BB * KK * 6;
}

__device__ inline ushort f2bf(float f) {
  uint32 u = __builtin_bit_cast(uint32, f);
  u += 0x7fffu + ((u >> 16) & 1u);
  return (ushort)(u >> 16);
}
__device__ inline uint32 pk2(float a, float b) {
  return (uint32)f2bf(a) | ((uint32)f2bf(b) << 16);
}
__device__ inline bf16x8 ld8(const ushort* p) {   // 16B from 8B-aligned LDS
  bf16x4 lo = *(const bf16x4*)(p);
  bf16x4 hi = *(const bf16x4*)(p + 4);
  return __builtin_shufflevector(lo, hi, 0, 1, 2, 3, 4, 5, 6, 7);
}

// ---------------- weight permutes ----------------
// W1[k][128][1][3][3] f32 -> W1p[k][co][32] bf16 (taps 0..8, zeros 9..31)
__global__ __launch_bounds__(128) void k_w1p(const float* __restrict__ W1,
                                             ushort* __restrict__ W1p) {
  const int k = blockIdx.x, co = threadIdx.x;
  ushort tmp[32];
  #pragma unroll
  for (int i = 0; i < 32; ++i) tmp[i] = 0;
  #pragma unroll
  for (int j = 0; j < 9; ++j) tmp[j] = f2bf(W1[(k * 128 + co) * 9 + j]);
  uint4* dp = (uint4*)(W1p + ((size_t)k * 128 + co) * 32);
  #pragma unroll
  for (int i = 0; i < 4; ++i) dp[i] = ((uint4*)tmp)[i];
}

// W[k][co][128ci][9] f32 -> Wp[k][c][j][co][cil] bf16
__global__ __launch_bounds__(256) void k_wp(const float* __restrict__ src,
                                            ushort* __restrict__ dst) {
  const int blk = blockIdx.x;            // 24*16
  const int k = blk >> 4;
  const int co = ((blk & 15) << 3) + (threadIdx.x >> 5);
  const int cil = threadIdx.x & 31;
  #pragma unroll
  for (int c = 0; c < 4; ++c) {
    const float* sp = src + ((size_t)(k * 128 + co) * 128 + c * 32 + cil) * 9;
    float v[9];
    #pragma unroll
    for (int j = 0; j < 9; ++j) v[j] = sp[j];
    ushort* dp = dst + (size_t)(k * 4 + c) * 9 * 128 * 32;
    #pragma unroll
    for (int j = 0; j < 9; ++j) dp[(j * 128 + co) * 32 + cil] = f2bf(v[j]);
  }
}

// ---------------- conv1(MFMA) + conv2 via MFMA, A from global ----------------
__global__ __launch_bounds__(256, 3) void k_conv2m(
    const float* __restrict__ x, const ushort* __restrict__ W1p, const float* __restrict__ b1,
    const ushort* __restrict__ W2p, const float* __restrict__ b2, ushort* __restrict__ h2T)
{
  const int kb = blockIdx.x;
  const int k = kb >> 7;
  const int b = kb & 127;
  const int t = threadIdx.x;

  __shared__ __align__(16) float xs[1600];
  __shared__ float b1s[128], b2s[128];
  __shared__ __align__(16) ushort xim[361 * 20];   // [pos][k0..15 + 4 pad]
  __shared__ __align__(16) ushort h1T[361 * 36];   // [pos][32 cil + 4 pad]
  __shared__ __align__(16) ushort zlds[8];

  for (int i = t; i < 400; i += 256)
    ((float4*)xs)[i] = ((const float4*)(x + (size_t)b * 1600))[i];
  if (t < 128) { b1s[t] = b1[k * 128 + t]; b2s[t] = b2[k * 128 + t]; }
  if (t < 8) zlds[t] = 0;
  __syncthreads();

  // build xim: per output pos, 9 taps of x (bf16), zeros to 16
  for (int f = t; f < 361; f += 256) {
    const int py = f / 19, px = f - 19 * py;
    const float* xp = &xs[py * 80 + px * 2];
    uint32 r0 = pk2(xp[0], xp[1]);
    uint32 r1 = pk2(xp[2], xp[40]);
    uint32 r2 = pk2(xp[41], xp[42]);
    uint32 r3 = pk2(xp[80], xp[81]);
    uint32 r4 = (uint32)f2bf(xp[82]);
    uint2* dp = (uint2*)(xim + f * 20);
    dp[0] = make_uint2(r0, r1);
    dp[1] = make_uint2(r2, r3);
    dp[2] = make_uint2(r4, 0u);
    dp[3] = make_uint2(0u, 0u);
    dp[4] = make_uint2(0u, 0u);
  }

  const int w = t >> 6, lane = t & 63, r = lane & 15, s = lane >> 4;
  const int m0 = (w & 1) * 64;       // conv2: 4 M-tiles
  const int n0 = (w >> 1) * 48;      // conv2: 3 N-tiles
  const int mt = w & 1;              // conv1 M-tile within chunk
  const int nh = w >> 1;             // conv1 N-half
  const int nt0 = nh ? 12 : 0, nt1 = nh ? 23 : 12;

  // conv2 B position bases
  int pb[3]; bool vld[3];
  #pragma unroll
  for (int ni = 0; ni < 3; ++ni) {
    const int n = n0 + 16 * ni + r;
    const int py = n / 9, px = n - 9 * py;
    pb[ni] = 38 * py + 2 * px;
    vld[ni] = (n < 81);
  }

  f32x4 acc[4][3];
  #pragma unroll
  for (int mi = 0; mi < 4; ++mi)
    #pragma unroll
    for (int ni = 0; ni < 3; ++ni) acc[mi][ni] = (f32x4){0.f, 0.f, 0.f, 0.f};

  for (int c = 0; c < 4; ++c) {
    __syncthreads();   // h1T safe to overwrite (prev chunk's MFMA done); xim ready (c=0)
    // ---- conv1 via MFMA: co tile = 32c+16mt, K=32 (9 valid) ----
    {
      const bf16x8 a1 = *(const bf16x8*)(W1p + ((size_t)k * 128 + 32 * c + 16 * mt + r) * 32 + 8 * s);
      for (int nt = nt0; nt < nt1; ++nt) {
        const int n = nt * 16 + r;
        const int pos = (n < 361) ? n : 360;
        const ushort* bp = (s < 2) ? (xim + pos * 20 + 8 * s) : zlds;
        const bf16x8 bv = ld8(bp);
        f32x4 cc = __builtin_amdgcn_mfma_f32_16x16x32_bf16(a1, bv, (f32x4){0.f, 0.f, 0.f, 0.f}, 0, 0, 0);
        if (n < 361) {
          const int cil0 = 16 * mt + 4 * s;
          const float bb0 = b1s[32 * c + cil0], bb1 = b1s[32 * c + cil0 + 1];
          const float bb2 = b1s[32 * c + cil0 + 2], bb3 = b1s[32 * c + cil0 + 3];
          uint2 pk;
          pk.x = pk2(fmaxf(cc[0] + bb0, 0.f), fmaxf(cc[1] + bb1, 0.f));
          pk.y = pk2(fmaxf(cc[2] + bb2, 0.f), fmaxf(cc[3] + bb3, 0.f));
          *(uint2*)(h1T + n * 36 + cil0) = pk;
        }
      }
    }
    __syncthreads();
    // ---- conv2 MFMA over 9 taps, A prefetched from global ----
    const ushort* Abase = W2p + ((((size_t)k * 4 + c) * 9) * 128 + m0 + r) * 32 + 8 * s;
    bf16x8 Ab[2][4];
    #pragma unroll
    for (int mi = 0; mi < 4; ++mi) Ab[0][mi] = *(const bf16x8*)(Abase + mi * 512);
    #pragma unroll
    for (int j = 0; j < 9; ++j) {
      if (j < 8) {
        #pragma unroll
        for (int mi = 0; mi < 4; ++mi)
          Ab[(j + 1) & 1][mi] = *(const bf16x8*)(Abase + (size_t)(j + 1) * 4096 + mi * 512);
      }
      const int off = (j / 3) * 19 + (j - 3 * (j / 3));
      bf16x8 Bv[3];
      #pragma unroll
      for (int ni = 0; ni < 3; ++ni) {
        const int pos = vld[ni] ? pb[ni] + off : 0;
        Bv[ni] = ld8(h1T + pos * 36 + 8 * s);
      }
      #pragma unroll
      for (int mi = 0; mi < 4; ++mi)
        #pragma unroll
        for (int ni = 0; ni < 3; ++ni)
          acc[mi][ni] = __builtin_amdgcn_mfma_f32_16x16x32_bf16(Ab[j & 1][mi], Bv[ni], acc[mi][ni], 0, 0, 0);
    }
  }

  // epilogue -> h2T[kb][p][co]
  #pragma unroll
  for (int mi = 0; mi < 4; ++mi)
    #pragma unroll
    for (int ni = 0; ni < 3; ++ni) {
      const int p = n0 + 16 * ni + r;
      if (p < 81) {
        const int co0 = m0 + 16 * mi + 4 * s;
        uint2 pk;
        pk.x = pk2(fmaxf(acc[mi][ni][0] + b2s[co0], 0.f), fmaxf(acc[mi][ni][1] + b2s[co0 + 1], 0.f));
        pk.y = pk2(fmaxf(acc[mi][ni][2] + b2s[co0 + 2], 0.f), fmaxf(acc[mi][ni][3] + b2s[co0 + 3], 0.f));
        *(uint2*)(h2T + (size_t)kb * 10368 + p * 128 + co0) = pk;
      }
    }
}

// ---------------- conv3 via MFMA ----------------
__global__ __launch_bounds__(256, 3) void k_conv3m(
    const ushort* __restrict__ h2T, const ushort* __restrict__ W3p,
    const float* __restrict__ b3, ushort* __restrict__ h3T)
{
  const int kb = blockIdx.x;
  const int k = kb >> 7;
  const int t = threadIdx.x;

  __shared__ float b3s[128];
  __shared__ __align__(16) ushort h2s[4 * 81 * 36];

  if (t < 128) b3s[t] = b3[k * 128 + t];
  for (int f = t; f < 2916; f += 256) {
    const int c = f / 729; const int rem = f - 729 * c;
    const int p = rem / 9; const int g = rem - 9 * p;
    *(uint2*)(h2s + (c * 81 + p) * 36 + 4 * g) =
        *(const uint2*)(h2T + (size_t)kb * 10368 + p * 128 + c * 32 + 4 * g);
  }
  __syncthreads();

  const int w = t >> 6, lane = t & 63, r = lane & 15, s = lane >> 4;
  const int m0 = (w & 1) * 64;
  const int n0 = (w >> 1) * 32;

  int pb[2]; bool vld[2];
  #pragma unroll
  for (int ni = 0; ni < 2; ++ni) {
    const int n = n0 + 16 * ni + r;
    const int py = n / 7, px = n - 7 * py;
    pb[ni] = 9 * py + px;
    vld[ni] = (n < 49);
  }

  f32x4 acc[4][2];
  #pragma unroll
  for (int mi = 0; mi < 4; ++mi)
    #pragma unroll
    for (int ni = 0; ni < 2; ++ni) acc[mi][ni] = (f32x4){0.f, 0.f, 0.f, 0.f};

  for (int c = 0; c < 4; ++c) {
    const ushort* Abase = W3p + ((((size_t)k * 4 + c) * 9) * 128 + m0 + r) * 32 + 8 * s;
    bf16x8 Ab[2][4];
    #pragma unroll
    for (int mi = 0; mi < 4; ++mi) Ab[0][mi] = *(const bf16x8*)(Abase + mi * 512);
    #pragma unroll
    for (int j = 0; j < 9; ++j) {
      if (j < 8) {
        #pragma unroll
        for (int mi = 0; mi < 4; ++mi)
          Ab[(j + 1) & 1][mi] = *(const bf16x8*)(Abase + (size_t)(j + 1) * 4096 + mi * 512);
      }
      const int off = (j / 3) * 9 + (j - 3 * (j / 3));
      bf16x8 Bv[2];
      #pragma unroll
      for (int ni = 0; ni < 2; ++ni) {
        const int pos = vld[ni] ? pb[ni] + off : 0;
        Bv[ni] = ld8(h2s + (c * 81 + pos) * 36 + 8 * s);
      }
      #pragma unroll
      for (int mi = 0; mi < 4; ++mi)
        #pragma unroll
        for (int ni = 0; ni < 2; ++ni)
          acc[mi][ni] = __builtin_amdgcn_mfma_f32_16x16x32_bf16(Ab[j & 1][mi], Bv[ni], acc[mi][ni], 0, 0, 0);
    }
  }

  #pragma unroll
  for (int mi = 0; mi < 4; ++mi)
    #pragma unroll
    for (int ni = 0; ni < 2; ++ni) {
      const int p = n0 + 16 * ni + r;
      if (p < 49) {
        const int co0 = m0 + 16 * mi + 4 * s;
        uint2 pk;
        pk.x = pk2(fmaxf(acc[mi][ni][0] + b3s[co0], 0.f), fmaxf(acc[mi][ni][1] + b3s[co0 + 1], 0.f));
        pk.y = pk2(fmaxf(acc[mi][ni][2] + b3s[co0 + 2], 0.f), fmaxf(acc[mi][ni][3] + b3s[co0 + 3], 0.f));
        *(uint2*)(h3T + (size_t)kb * 6272 + p * 128 + co0) = pk;
      }
    }
}

// ---------------- conv4 MFMA + conv5 + att softmax + pooling ----------------
__global__ __launch_bounds__(256, 3) void k_conv45m(
    const ushort* __restrict__ h3T, const ushort* __restrict__ W4p, const float* __restrict__ b4,
    const float* __restrict__ W5, const float* __restrict__ b5, float* __restrict__ pooled)
{
  const int kb = blockIdx.x;
  const int k = kb >> 7;
  const int b = kb & 127;
  const int t = threadIdx.x;

  __shared__ float b4s[128];
  __shared__ __align__(16) ushort h3s[4 * 49 * 36];
  __shared__ float h4s[128 * 26];
  __shared__ float w5s[3072];
  __shared__ float b5s[24];
  __shared__ float outs_s[600];
  __shared__ float att_s[25];

  if (t < 128) b4s[t] = b4[k * 128 + t];
  for (int i = t; i < 3072; i += 256) w5s[i] = W5[k * 3072 + i];
  if (t < 24) b5s[t] = b5[k * 24 + t];
  for (int f = t; f < 1764; f += 256) {
    const int c = f / 441; const int rem = f - 441 * c;
    const int p = rem / 9; const int g = rem - 9 * p;
    *(uint2*)(h3s + (c * 49 + p) * 36 + 4 * g) =
        *(const uint2*)(h3T + (size_t)kb * 6272 + p * 128 + c * 32 + 4 * g);
  }
  __syncthreads();

  const int w = t >> 6, lane = t & 63, r = lane & 15, s = lane >> 4;
  const int m0 = w * 32;

  int pb[2]; bool vld[2];
  #pragma unroll
  for (int ni = 0; ni < 2; ++ni) {
    const int n = 16 * ni + r;
    const int py = n / 5, px = n - 5 * py;
    pb[ni] = 7 * py + px;
    vld[ni] = (n < 25);
  }

  f32x4 acc[2][2];
  #pragma unroll
  for (int mi = 0; mi < 2; ++mi)
    #pragma unroll
    for (int ni = 0; ni < 2; ++ni) acc[mi][ni] = (f32x4){0.f, 0.f, 0.f, 0.f};

  for (int c = 0; c < 4; ++c) {
    const ushort* Abase = W4p + ((((size_t)k * 4 + c) * 9) * 128 + m0 + r) * 32 + 8 * s;
    bf16x8 Ab[2][2];
    #pragma unroll
    for (int mi = 0; mi < 2; ++mi) Ab[0][mi] = *(const bf16x8*)(Abase + mi * 512);
    #pragma unroll
    for (int j = 0; j < 9; ++j) {
      if (j < 8) {
        #pragma unroll
        for (int mi = 0; mi < 2; ++mi)
          Ab[(j + 1) & 1][mi] = *(const bf16x8*)(Abase + (size_t)(j + 1) * 4096 + mi * 512);
      }
      const int off = (j / 3) * 7 + (j - 3 * (j / 3));
      bf16x8 Bv[2];
      #pragma unroll
      for (int ni = 0; ni < 2; ++ni) {
        const int pos = vld[ni] ? pb[ni] + off : 0;
        Bv[ni] = ld8(h3s + (c * 49 + pos) * 36 + 8 * s);
      }
      #pragma unroll
      for (int mi = 0; mi < 2; ++mi)
        #pragma unroll
        for (int ni = 0; ni < 2; ++ni)
          acc[mi][ni] = __builtin_amdgcn_mfma_f32_16x16x32_bf16(Ab[j & 1][mi], Bv[ni], acc[mi][ni], 0, 0, 0);
    }
  }

  #pragma unroll
  for (int mi = 0; mi < 2; ++mi)
    #pragma unroll
    for (int ni = 0; ni < 2; ++ni) {
      const int p = 16 * ni + r;
      if (p < 25) {
        #pragma unroll
        for (int rg = 0; rg < 4; ++rg) {
          const int co = m0 + 16 * mi + 4 * s + rg;
          h4s[co * 26 + p] = fmaxf(acc[mi][ni][rg] + b4s[co], 0.0f);
        }
      }
    }
  __syncthreads();

  for (int o = t; o < 600; o += 256) {
    const int fm = o / 25;
    const int p = o - fm * 25;
    float v = b5s[fm];
    const float* wp = &w5s[fm * 128];
    #pragma unroll 8
    for (int ci = 0; ci < 128; ++ci) v = fmaf(wp[ci], h4s[ci * 26 + p], v);
    outs_s[o] = v;
  }
  __syncthreads();

  if (t < 64) {
    float v = (t < 25) ? outs_s[575 + t] : -1e30f;
    #pragma unroll
    for (int off = 32; off; off >>= 1) v = fmaxf(v, __shfl_xor(v, off));
    const float m = v;
    float e = (t < 25) ? expf(outs_s[575 + t] - m) : 0.0f;
    float ss = e;
    #pragma unroll
    for (int off = 32; off; off >>= 1) ss += __shfl_xor(ss, off);
    if (t < 25) att_s[t] = e / ss;
  }
  __syncthreads();

  if (t < 23) {
    float v = 0.f;
    #pragma unroll
    for (int p = 0; p < 25; ++p) v = fmaf(outs_s[t * 25 + p], att_s[p], v);
    pooled[(size_t)(b * KK + k) * 23 + t] = v;
  }
}

// ---------------- pose -> warp templates -> softmax stats ----------------
__device__ inline float tapf(const float* tm, int yi, int xi) {
  const bool ok = (xi >= 0) & (xi < 11) & (yi >= 0) & (yi < 11);
  const int yc = min(max(yi, 0), 10), xc = min(max(xi, 0), 10);
  const float v = tm[yc * 11 + xc];
  return ok ? v : 0.0f;
}

__global__ __launch_bounds__(256) void k_pose_warp(
    const float* __restrict__ pooled, const float* __restrict__ noise,
    const float* __restrict__ templates, float* __restrict__ out,
    float* __restrict__ tt, float* __restrict__ smax, float* __restrict__ sden,
    float* __restrict__ dmw)
{
  const int bk = blockIdx.x;
  const int b = bk / KK;
  const int k = bk - b * KK;
  const int t = threadIdx.x;

  __shared__ float ps[23];
  __shared__ float tm[121];
  __shared__ float red[4];

  if (t < 23) ps[t] = pooled[(size_t)(b * KK + k) * 23 + t];
  for (int i = t; i < 121; i += 256) tm[i] = templates[k * 121 + i];
  __syncthreads();

  float xm[6];
  #pragma unroll
  for (int j = 0; j < 6; ++j) xm[j] = fmaxf(ps[j], 0.0f);
  const float dl = ps[6] + noise[b * KK + k];
  const float dm = 1.0f / (1.0f + expf(-dl));

  const size_t obase = O_OCAE + (size_t)(b * KK + k) * 144;
  if (t < 144) {
    float v;
    if (t == 0)       v = dm;
    else if (t < 7)   v = xm[t - 1];
    else if (t < 128) v = tm[t - 7];
    else              v = fmaxf(ps[7 + (t - 128)], 0.0f);
    out[obase + t] = v;
  }
  if (t < 6) out[O_XM + (size_t)(b * KK + k) * 6 + t] = xm[t];
  if (t == 0) out[O_DM + (b * KK + k)] = dm;

  const float D2R = 0.017453292519943295f;
  const float ang = xm[0] * D2R;
  const float tx = xm[1], ty = xm[2];
  const float sc = xm[3] + 1e-6f;
  const float sxr = xm[4] * D2R, syr = xm[5] * D2R;
  const float cas = cosf(ang - syr), sas = sinf(ang - syr);
  const float csy = cosf(syr), tsx = tanf(sxr);
  const float a_ = cas / csy;
  const float b_ = -cas * tsx / csy - sinf(ang);
  const float c_ = sas / csy;
  const float d_ = -sas * tsx / csy + cosf(ang);
  const float m00 = d_ / sc, m01 = -b_ / sc, m10 = -c_ / sc, m11 = a_ / sc;
  const float m02 = m00 * (-5.0f - tx) + m01 * (-5.0f - ty) + 5.0f;
  const float m12 = m10 * (-5.0f - tx) + m11 * (-5.0f - ty) + 5.0f;

  const float S = 0.275f;
  float ttv[7];
  float lmax = -1e30f;
  #pragma unroll
  for (int i = 0; i < 7; ++i) {
    const int pix = t + 256 * i;
    float val = 0.0f;
    if (pix < 1600) {
      const int py = pix / 40, px = pix - 40 * py;
      const float u = (px + 0.5f) * S - 0.5f;
      const float v = (py + 0.5f) * S - 0.5f;
      const float sx = m00 * u + m01 * v + m02;
      const float sy = m10 * u + m11 * v + m12;
      const float x0 = floorf(sx), y0 = floorf(sy);
      const float wx = sx - x0, wy = sy - y0;
      const int xi = (int)x0, yi = (int)y0;
      const float v00 = tapf(tm, yi, xi);
      const float v01 = tapf(tm, yi, xi + 1);
      const float v10 = tapf(tm, yi + 1, xi);
      const float v11 = tapf(tm, yi + 1, xi + 1);
      val = (v00 * (1.0f - wx) + v01 * wx) * (1.0f - wy) + (v10 * (1.0f - wx) + v11 * wx) * wy;
      tt[(size_t)(b * KK + k) * 1600 + pix] = val;
      lmax = fmaxf(lmax, dm * val);
    }
    ttv[i] = val;
  }

  #pragma unroll
  for (int off = 32; off; off >>= 1) lmax = fmaxf(lmax, __shfl_xor(lmax, off));
  if ((t & 63) == 0) red[t >> 6] = lmax;
  __syncthreads();
  const float m = fmaxf(fmaxf(red[0], red[1]), fmaxf(red[2], red[3]));
  float ls = 0.0f;
  #pragma unroll
  for (int i = 0; i < 7; ++i)
    if (t + 256 * i < 1600) ls += expf(fmaf(dm, ttv[i], -m));
  #pragma unroll
  for (int off = 32; off; off >>= 1) ls += __shfl_xor(ls, off);
  __syncthreads();
  if ((t & 63) == 0) red[t >> 6] = ls;
  __syncthreads();
  if (t == 0) {
    smax[b * KK + k] = m;
    sden[b * KK + k] = red[0] + red[1] + red[2] + red[3];
    dmw[b * KK + k] = dm;
  }
}

// ---------------- per-pixel mixture + log; partial sums ----------------
__global__ __launch_bounds__(256) void k_ll(
    const float* __restrict__ x, const float* __restrict__ tt,
    const float* __restrict__ smax, const float* __restrict__ sden,
    const float* __restrict__ dmw, float* __restrict__ part)
{
  const int b = blockIdx.x >> 2;
  const int chunk = blockIdx.x & 3;
  const int t = threadIdx.x;

  __shared__ __align__(16) float xs[1600];
  __shared__ float kd[24], km[24], ki[24];
  __shared__ float red[4], red2[4];

  for (int i = t; i < 400; i += 256)
    ((float4*)xs)[i] = ((const float4*)(x + (size_t)b * 1600))[i];
  if (t < 24) {
    kd[t] = dmw[b * 24 + t];
    km[t] = smax[b * 24 + t];
    ki[t] = 1.0f / sden[b * 24 + t];
  }
  __syncthreads();

  float s1 = 0.f, s2 = 0.f;
  for (int i = t; i < 1600; i += 256) { const float v = xs[i]; s1 += v; s2 = fmaf(v, v, s2); }
  #pragma unroll
  for (int off = 32; off; off >>= 1) { s1 += __shfl_xor(s1, off); s2 += __shfl_xor(s2, off); }
  if ((t & 63) == 0) { red[t >> 6] = s1; red2[t >> 6] = s2; }
  __syncthreads();
  s1 = red[0] + red[1] + red[2] + red[3];
  s2 = red2[0] + red2[1] + red2[2] + red2[3];
  const float var = (s2 - s1 * s1 * (1.0f / 1600.0f)) * (1.0f / 1599.0f);
  const float stdv = sqrtf(var);
  const float mult = 1.0f / sqrtf(stdv * 6.283185307179586f);
  const float pmul = -1.0f / (2.0f * stdv * stdv);

  const int p0 = chunk * 400;
  float ll = 0.0f;
  for (int ii = t; ii < 400; ii += 256) {
    const int pix = p0 + ii;
    const float xv = xs[pix];
    float sum = 0.0f;
    #pragma unroll 6
    for (int kk2 = 0; kk2 < 24; ++kk2) {
      const float tv = tt[(size_t)(b * 24 + kk2) * 1600 + pix];
      const float dxv = xv - tv;
      sum += expf(fmaf(dxv * dxv, pmul, fmaf(kd[kk2], tv, -km[kk2]))) * ki[kk2];
    }
    ll += logf(mult * sum);
  }
  #pragma unroll
  for (int off = 32; off; off >>= 1) ll += __shfl_xor(ll, off);
  __syncthreads();
  if ((t & 63) == 0) red[t >> 6] = ll;
  __syncthreads();
  if (t == 0) part[blockIdx.x] = red[0] + red[1] + red[2] + red[3];
}

__global__ void k_final(const float* __restrict__ part, float* __restrict__ out)
{
  const int t = threadIdx.x;
  float v = part[t] + part[t + 256];
  #pragma unroll
  for (int off = 32; off; off >>= 1) v += __shfl_xor(v, off);
  __shared__ float red[4];
  if ((t & 63) == 0) red[t >> 6] = v;
  __syncthreads();
  if (t == 0) out[0] = (red[0] + red[1] + red[2] + red[3]) * (1.0f / 128.0f);
}

extern "C" void kernel_launch(void* const* d_in, const int* in_sizes, int n_in,
                              void* d_out, int out_size, void* d_ws, size_t ws_size,
                              hipStream_t stream)
{
  const float* x     = (const float*)d_in[0];
  const float* noise = (const float*)d_in[1];
  const float* W1    = (const float*)d_in[2];
  const float* b1    = (const float*)d_in[3];
  const float* W2    = (const float*)d_in[4];
  const float* b2    = (const float*)d_in[5];
  const float* W3    = (const float*)d_in[6];
  const float* b3    = (const float*)d_in[7];
  const float* W4    = (const float*)d_in[8];
  const float* b4    = (const float*)d_in[9];
  const float* W5    = (const float*)d_in[10];
  const float* b5    = (const float*)d_in[11];
  const float* tmpl  = (const float*)d_in[12];
  float* out = (float*)d_out;
  char* wsb = (char*)d_ws;

  ushort* W1p = (ushort*)(wsb + OFF_W1P);
  ushort* W2p = (ushort*)(wsb + OFF_WB2);
  ushort* W3p = (ushort*)(wsb + OFF_WB3);
  ushort* W4p = (ushort*)(wsb + OFF_WB4);
  ushort* h2T = (ushort*)(wsb + OFF_H2T);
  ushort* h3T = (ushort*)(wsb + OFF_H3T);
  float* poolp = (float*)(wsb + OFF_POOL);
  float* ttp   = (float*)(wsb + OFF_TT);
  float* smaxp = (float*)(wsb + OFF_SMAX);
  float* sdenp = (float*)(wsb + OFF_SDEN);
  float* dmp   = (float*)(wsb + OFF_DM);
  float* partp = (float*)(wsb + OFF_PART);

  k_w1p<<<24, 128, 0, stream>>>(W1, W1p);
  k_wp<<<384, 256, 0, stream>>>(W2, W2p);
  k_wp<<<384, 256, 0, stream>>>(W3, W3p);
  k_wp<<<384, 256, 0, stream>>>(W4, W4p);
  k_conv2m<<<KK * BB, 256, 0, stream>>>(x, W1p, b1, W2p, b2, h2T);
  k_conv3m<<<KK * BB, 256, 0, stream>>>(h2T, W3p, b3, h3T);
  k_conv45m<<<KK * BB, 256, 0, stream>>>(h3T, W4p, b4, W5, b5, poolp);
  k_pose_warp<<<BB * KK, 256, 0, stream>>>(poolp, noise, tmpl, out, ttp, smaxp, sdenp, dmp);
  k_ll<<<BB * 4, 256, 0, stream>>>(x, ttp, smaxp, sdenp, dmp, partp);
  k_final<<<1, 256, 0, stream>>>(partp, out);
}

// Round 5
// 349.141 us; speedup vs baseline: 15.3904x; 1.1811x over previous
//
#include <hip/hip_runtime.h>
#include <math.h>

typedef __attribute__((ext_vector_type(8))) short bf16x8;
typedef __attribute__((ext_vector_type(4))) float f32x4;
typedef unsigned int uint32;
typedef unsigned short ushort;

namespace {
constexpr int KK = 24, BB = 128;

// ---- workspace byte offsets ----
constexpr size_t SZ_W1P = (size_t)24 * 128 * 32 * 2;
constexpr size_t SZ_WB  = (size_t)24 * 128 * 1152 * 2;            // 7,077,888
constexpr size_t OFF_W1P = 0;
constexpr size_t OFF_WB2 = OFF_W1P + SZ_W1P;
constexpr size_t OFF_WB3 = OFF_WB2 + SZ_WB;
constexpr size_t OFF_WB4 = OFF_WB3 + SZ_WB;
constexpr size_t OFF_H2T = OFF_WB4 + SZ_WB;                       // bf16 [kb][81][128]
constexpr size_t SZ_H2T  = (size_t)3072 * 81 * 128 * 2;
constexpr size_t OFF_H3T = OFF_H2T + SZ_H2T;                      // bf16 [kb][49][128]
constexpr size_t SZ_H3T  = (size_t)3072 * 49 * 128 * 2;
constexpr size_t OFF_POOL = OFF_H3T + SZ_H3T;
constexpr size_t SZ_POOL  = (size_t)128 * 24 * 23 * 4;
constexpr size_t OFF_TT   = OFF_POOL + SZ_POOL;
constexpr size_t SZ_TT    = (size_t)128 * 24 * 1600 * 4;
constexpr size_t OFF_SMAX = OFF_TT + SZ_TT;
constexpr size_t OFF_SDEN = OFF_SMAX + 12288;
constexpr size_t OFF_DM   = OFF_SDEN + 12288;
constexpr size_t OFF_PART = OFF_DM + 12288;

// ---- output offsets (floats) ----
constexpr long long O_OCAE = 1;
constexpr long long O_XM   = O_OCAE + (long long)BB * KK * 144;
constexpr long long O_DM   = O_XM + (long long)BB * KK * 6;
}

__device__ inline ushort f2bf(float f) {
  uint32 u = __builtin_bit_cast(uint32, f);
  u += 0x7fffu + ((u >> 16) & 1u);
  return (ushort)(u >> 16);
}
__device__ inline uint32 pk2(float a, float b) {
  return (uint32)f2bf(a) | ((uint32)f2bf(b) << 16);
}

// ---------------- weight permutes ----------------
// W1[k][128][1][3][3] f32 -> W1p[k][co][32] bf16 (taps 0..8, zeros 9..31)
__global__ __launch_bounds__(128) void k_w1p(const float* __restrict__ W1,
                                             ushort* __restrict__ W1p) {
  const int k = blockIdx.x, co = threadIdx.x;
  ushort tmp[32];
  #pragma unroll
  for (int i = 0; i < 32; ++i) tmp[i] = 0;
  #pragma unroll
  for (int j = 0; j < 9; ++j) tmp[j] = f2bf(W1[(k * 128 + co) * 9 + j]);
  uint4* dp = (uint4*)(W1p + ((size_t)k * 128 + co) * 32);
  #pragma unroll
  for (int i = 0; i < 4; ++i) dp[i] = ((uint4*)tmp)[i];
}

// W[k][co][128ci][9] f32 -> Wp[k][c][j][co][cil] bf16  (all three weights in one launch)
__global__ __launch_bounds__(256) void k_wp(
    const float* __restrict__ W2, const float* __restrict__ W3, const float* __restrict__ W4,
    ushort* __restrict__ W2p, ushort* __restrict__ W3p, ushort* __restrict__ W4p) {
  const int blk = blockIdx.x;            // 3*384
  const int sel = blk / 384;
  const int bb = blk - sel * 384;
  const float* src = (sel == 0) ? W2 : (sel == 1) ? W3 : W4;
  ushort* dst = (sel == 0) ? W2p : (sel == 1) ? W3p : W4p;
  const int k = bb >> 4;
  const int co = ((bb & 15) << 3) + (threadIdx.x >> 5);
  const int cil = threadIdx.x & 31;
  #pragma unroll
  for (int c = 0; c < 4; ++c) {
    const float* sp = src + ((size_t)(k * 128 + co) * 128 + c * 32 + cil) * 9;
    float v[9];
    #pragma unroll
    for (int j = 0; j < 9; ++j) v[j] = sp[j];
    ushort* dp = dst + (size_t)(k * 4 + c) * 9 * 128 * 32;
    #pragma unroll
    for (int j = 0; j < 9; ++j) dp[(j * 128 + co) * 32 + cil] = f2bf(v[j]);
  }
}

// ---------------- conv1(MFMA) + conv2 via MFMA, A from global ----------------
__global__ __launch_bounds__(256, 3) void k_conv2m(
    const float* __restrict__ x, const ushort* __restrict__ W1p, const float* __restrict__ b1,
    const ushort* __restrict__ W2p, const float* __restrict__ b2, ushort* __restrict__ h2T)
{
  const int bi = blockIdx.x;
  const int kb = (bi & 7) * 384 + (bi >> 3);   // XCD swizzle (3072/8=384)
  const int k = kb >> 7;
  const int b = kb & 127;
  const int t = threadIdx.x;

  __shared__ __align__(16) char pool[361 * 40 * 2];   // h1T [pos][40]; xs aliased (dead after xim)
  __shared__ float b1s[128], b2s[128];
  __shared__ __align__(16) ushort xim[361 * 24];      // [pos][9 taps + zeros to 16 + pad]
  __shared__ __align__(16) ushort zlds[8];
  ushort* h1T = (ushort*)pool;
  float* xs = (float*)pool;

  for (int i = t; i < 400; i += 256)
    ((float4*)xs)[i] = ((const float4*)(x + (size_t)b * 1600))[i];
  if (t < 128) { b1s[t] = b1[k * 128 + t]; b2s[t] = b2[k * 128 + t]; }
  if (t < 8) zlds[t] = 0;
  __syncthreads();

  // build xim from xs (xs dies after this; h1T overlays it from chunk 0 on)
  for (int f = t; f < 361; f += 256) {
    const int py = f / 19, px = f - 19 * py;
    const float* xp = &xs[py * 80 + px * 2];
    uint32 r0 = pk2(xp[0], xp[1]);
    uint32 r1 = pk2(xp[2], xp[40]);
    uint32 r2 = pk2(xp[41], xp[42]);
    uint32 r3 = pk2(xp[80], xp[81]);
    uint32 r4 = (uint32)f2bf(xp[82]);
    uint4* dp = (uint4*)(xim + f * 24);
    dp[0] = make_uint4(r0, r1, r2, r3);
    dp[1] = make_uint4(r4, 0u, 0u, 0u);
    dp[2] = make_uint4(0u, 0u, 0u, 0u);
  }

  const int w = t >> 6, lane = t & 63, r = lane & 15, s = lane >> 4;
  const int m0 = (w & 1) * 64;       // conv2: 4 M-tiles
  const int n0 = (w >> 1) * 48;      // conv2: 3 N-tiles
  const int mt = w & 1;              // conv1 M-tile within chunk
  const int nh = w >> 1;             // conv1 N-half
  const int nt0 = nh ? 12 : 0, nt1 = nh ? 23 : 12;

  int pb[3]; bool vld[3];
  #pragma unroll
  for (int ni = 0; ni < 3; ++ni) {
    const int n = n0 + 16 * ni + r;
    const int py = n / 9, px = n - 9 * py;
    pb[ni] = 38 * py + 2 * px;
    vld[ni] = (n < 81);
  }

  f32x4 acc[4][3];
  #pragma unroll
  for (int mi = 0; mi < 4; ++mi)
    #pragma unroll
    for (int ni = 0; ni < 3; ++ni) acc[mi][ni] = (f32x4){0.f, 0.f, 0.f, 0.f};

  for (int c = 0; c < 4; ++c) {
    __syncthreads();   // prev chunk's conv2 reads done; (c=0) xim build done
    // ---- conv1 via MFMA: co tile = 32c+16mt, K=32 (9 valid) ----
    {
      const bf16x8 a1 = *(const bf16x8*)(W1p + ((size_t)k * 128 + 32 * c + 16 * mt + r) * 32 + 8 * s);
      for (int nt = nt0; nt < nt1; ++nt) {
        const int n = nt * 16 + r;
        const int pos = (n < 361) ? n : 360;
        const ushort* bp = (s < 2) ? (xim + pos * 24 + 8 * s) : zlds;
        const bf16x8 bv = *(const bf16x8*)bp;
        f32x4 cc = __builtin_amdgcn_mfma_f32_16x16x32_bf16(a1, bv, (f32x4){0.f, 0.f, 0.f, 0.f}, 0, 0, 0);
        if (n < 361) {
          const int cil0 = 16 * mt + 4 * s;
          const float bb0 = b1s[32 * c + cil0], bb1 = b1s[32 * c + cil0 + 1];
          const float bb2 = b1s[32 * c + cil0 + 2], bb3 = b1s[32 * c + cil0 + 3];
          uint2 pk;
          pk.x = pk2(fmaxf(cc[0] + bb0, 0.f), fmaxf(cc[1] + bb1, 0.f));
          pk.y = pk2(fmaxf(cc[2] + bb2, 0.f), fmaxf(cc[3] + bb3, 0.f));
          *(uint2*)(h1T + n * 40 + cil0) = pk;
        }
      }
    }
    __syncthreads();
    // ---- conv2 MFMA over 9 taps, A prefetched from global ----
    const ushort* Abase = W2p + ((((size_t)k * 4 + c) * 9) * 128 + m0 + r) * 32 + 8 * s;
    bf16x8 Ab[2][4];
    #pragma unroll
    for (int mi = 0; mi < 4; ++mi) Ab[0][mi] = *(const bf16x8*)(Abase + mi * 512);
    #pragma unroll
    for (int j = 0; j < 9; ++j) {
      if (j < 8) {
        #pragma unroll
        for (int mi = 0; mi < 4; ++mi)
          Ab[(j + 1) & 1][mi] = *(const bf16x8*)(Abase + (size_t)(j + 1) * 4096 + mi * 512);
      }
      const int off = (j / 3) * 19 + (j - 3 * (j / 3));
      bf16x8 Bv[3];
      #pragma unroll
      for (int ni = 0; ni < 3; ++ni) {
        const int pos = vld[ni] ? pb[ni] + off : 0;
        Bv[ni] = *(const bf16x8*)(h1T + pos * 40 + 8 * s);
      }
      #pragma unroll
      for (int mi = 0; mi < 4; ++mi)
        #pragma unroll
        for (int ni = 0; ni < 3; ++ni)
          acc[mi][ni] = __builtin_amdgcn_mfma_f32_16x16x32_bf16(Ab[j & 1][mi], Bv[ni], acc[mi][ni], 0, 0, 0);
    }
  }

  // epilogue -> h2T[kb][p][co]
  #pragma unroll
  for (int mi = 0; mi < 4; ++mi)
    #pragma unroll
    for (int ni = 0; ni < 3; ++ni) {
      const int p = n0 + 16 * ni + r;
      if (p < 81) {
        const int co0 = m0 + 16 * mi + 4 * s;
        uint2 pk;
        pk.x = pk2(fmaxf(acc[mi][ni][0] + b2s[co0], 0.f), fmaxf(acc[mi][ni][1] + b2s[co0 + 1], 0.f));
        pk.y = pk2(fmaxf(acc[mi][ni][2] + b2s[co0 + 2], 0.f), fmaxf(acc[mi][ni][3] + b2s[co0 + 3], 0.f));
        *(uint2*)(h2T + (size_t)kb * 10368 + p * 128 + co0) = pk;
      }
    }
}

// ---------------- conv3 via MFMA, 2 images per block, N=98 over 7 tiles ----------------
__global__ __launch_bounds__(256, 3) void k_conv3m(
    const ushort* __restrict__ h2T, const ushort* __restrict__ W3p,
    const float* __restrict__ b3, ushort* __restrict__ h3T)
{
  const int bi = blockIdx.x;
  const int blk = (bi & 7) * 192 + (bi >> 3);   // XCD swizzle (1536/8=192)
  const int kb0 = blk * 2;
  const int k = kb0 >> 8;                        // kb0>>7 /... kb0 = 2*blk, k = kb0/128
  const int kk = kb0 >> 7;
  const int t = threadIdx.x;

  __shared__ float b3s[128];
  __shared__ __align__(16) ushort h2s[2 * 4 * 81 * 40];   // 51.8 KB  [sel][c][pos][40]

  if (t < 128) b3s[t] = b3[kk * 128 + t];
  for (int f = t; f < 5184; f += 256) {
    const int sel = f / 2592; const int rem = f - sel * 2592;
    const int c = rem / 648; const int rem2 = rem - c * 648;
    const int p = rem2 >> 3; const int g = rem2 & 7;
    *(uint2*)(h2s + sel * 12960 + (c * 81 + p) * 40 + 4 * g) =
        *(const uint2*)(h2T + (size_t)(kb0 + sel) * 10368 + p * 128 + c * 32 + 4 * g);
  }
  __syncthreads();

  const int w = t >> 6, lane = t & 63, r = lane & 15, s = lane >> 4;
  const int m0 = (w & 1) * 64;
  const int ng = w >> 1;            // 0 -> N-tiles 0..3, 1 -> N-tiles 4..6
  const int n0 = ng * 64;
  const int NT = ng ? 3 : 4;

  int base[4];
  #pragma unroll
  for (int ni = 0; ni < 4; ++ni) {
    const int n = n0 + 16 * ni + r;
    const int sel = (n >= 49 && n < 98) ? 1 : 0;
    const int pl = (n < 98) ? (n - 49 * sel) : 0;
    const int py = pl / 7, px = pl - 7 * py;
    base[ni] = sel * 12960 + (9 * py + px) * 40 + 8 * s;
  }

  f32x4 acc[4][4];
  #pragma unroll
  for (int mi = 0; mi < 4; ++mi)
    #pragma unroll
    for (int ni = 0; ni < 4; ++ni) acc[mi][ni] = (f32x4){0.f, 0.f, 0.f, 0.f};

  for (int c = 0; c < 4; ++c) {
    const ushort* Abase = W3p + ((((size_t)kk * 4 + c) * 9) * 128 + m0 + r) * 32 + 8 * s;
    bf16x8 Ab[2][4];
    #pragma unroll
    for (int mi = 0; mi < 4; ++mi) Ab[0][mi] = *(const bf16x8*)(Abase + mi * 512);
    #pragma unroll
    for (int j = 0; j < 9; ++j) {
      if (j < 8) {
        #pragma unroll
        for (int mi = 0; mi < 4; ++mi)
          Ab[(j + 1) & 1][mi] = *(const bf16x8*)(Abase + (size_t)(j + 1) * 4096 + mi * 512);
      }
      const int off40 = ((j / 3) * 9 + (j - 3 * (j / 3))) * 40;
      bf16x8 Bv[4];
      #pragma unroll
      for (int ni = 0; ni < 4; ++ni)
        if (ni < NT) Bv[ni] = *(const bf16x8*)(h2s + base[ni] + c * 3240 + off40);
      #pragma unroll
      for (int mi = 0; mi < 4; ++mi)
        #pragma unroll
        for (int ni = 0; ni < 4; ++ni)
          if (ni < NT)
            acc[mi][ni] = __builtin_amdgcn_mfma_f32_16x16x32_bf16(Ab[j & 1][mi], Bv[ni], acc[mi][ni], 0, 0, 0);
    }
  }

  #pragma unroll
  for (int mi = 0; mi < 4; ++mi)
    #pragma unroll
    for (int ni = 0; ni < 4; ++ni) {
      if (ni < NT) {
        const int n = n0 + 16 * ni + r;
        if (n < 98) {
          const int sel = (n >= 49) ? 1 : 0;
          const int pl = n - 49 * sel;
          const int co0 = m0 + 16 * mi + 4 * s;
          uint2 pk;
          pk.x = pk2(fmaxf(acc[mi][ni][0] + b3s[co0], 0.f), fmaxf(acc[mi][ni][1] + b3s[co0 + 1], 0.f));
          pk.y = pk2(fmaxf(acc[mi][ni][2] + b3s[co0 + 2], 0.f), fmaxf(acc[mi][ni][3] + b3s[co0 + 3], 0.f));
          *(uint2*)(h3T + (size_t)(kb0 + sel) * 6272 + pl * 128 + co0) = pk;
        }
      }
    }
}

// ---------------- conv4 MFMA + conv5 + att softmax + pooling ----------------
__global__ __launch_bounds__(256, 3) void k_conv45m(
    const ushort* __restrict__ h3T, const ushort* __restrict__ W4p, const float* __restrict__ b4,
    const float* __restrict__ W5, const float* __restrict__ b5, float* __restrict__ pooled)
{
  const int bi = blockIdx.x;
  const int kb = (bi & 7) * 384 + (bi >> 3);
  const int k = kb >> 7;
  const int b = kb & 127;
  const int t = threadIdx.x;

  __shared__ float b4s[128];
  __shared__ __align__(16) ushort h3s[4 * 49 * 40];   // 15.7 KB
  __shared__ float h4s[128 * 26];
  __shared__ float w5s[3072];
  __shared__ float b5s[24];
  __shared__ float outs_s[600];
  __shared__ float att_s[25];

  if (t < 128) b4s[t] = b4[k * 128 + t];
  for (int i = t; i < 3072; i += 256) w5s[i] = W5[k * 3072 + i];
  if (t < 24) b5s[t] = b5[k * 24 + t];
  for (int f = t; f < 1568; f += 256) {
    const int c = f / 392; const int rem = f - c * 392;
    const int p = rem >> 3; const int g = rem & 7;
    *(uint2*)(h3s + (c * 49 + p) * 40 + 4 * g) =
        *(const uint2*)(h3T + (size_t)kb * 6272 + p * 128 + c * 32 + 4 * g);
  }
  __syncthreads();

  const int w = t >> 6, lane = t & 63, r = lane & 15, s = lane >> 4;
  const int m0 = w * 32;

  int base[2]; bool vld[2];
  #pragma unroll
  for (int ni = 0; ni < 2; ++ni) {
    const int n = 16 * ni + r;
    const int py = n / 5, px = n - 5 * py;
    base[ni] = ((n < 25) ? (7 * py + px) : 0) * 40 + 8 * s;
    vld[ni] = (n < 25);
  }

  f32x4 acc[2][2];
  #pragma unroll
  for (int mi = 0; mi < 2; ++mi)
    #pragma unroll
    for (int ni = 0; ni < 2; ++ni) acc[mi][ni] = (f32x4){0.f, 0.f, 0.f, 0.f};

  for (int c = 0; c < 4; ++c) {
    const ushort* Abase = W4p + ((((size_t)k * 4 + c) * 9) * 128 + m0 + r) * 32 + 8 * s;
    bf16x8 Ab[2][2];
    #pragma unroll
    for (int mi = 0; mi < 2; ++mi) Ab[0][mi] = *(const bf16x8*)(Abase + mi * 512);
    #pragma unroll
    for (int j = 0; j < 9; ++j) {
      if (j < 8) {
        #pragma unroll
        for (int mi = 0; mi < 2; ++mi)
          Ab[(j + 1) & 1][mi] = *(const bf16x8*)(Abase + (size_t)(j + 1) * 4096 + mi * 512);
      }
      const int off40 = ((j / 3) * 7 + (j - 3 * (j / 3))) * 40;
      bf16x8 Bv[2];
      #pragma unroll
      for (int ni = 0; ni < 2; ++ni)
        Bv[ni] = *(const bf16x8*)(h3s + c * 1960 + base[ni] + off40);
      #pragma unroll
      for (int mi = 0; mi < 2; ++mi)
        #pragma unroll
        for (int ni = 0; ni < 2; ++ni)
          acc[mi][ni] = __builtin_amdgcn_mfma_f32_16x16x32_bf16(Ab[j & 1][mi], Bv[ni], acc[mi][ni], 0, 0, 0);
    }
  }

  #pragma unroll
  for (int mi = 0; mi < 2; ++mi)
    #pragma unroll
    for (int ni = 0; ni < 2; ++ni) {
      const int p = 16 * ni + r;
      if (p < 25) {
        #pragma unroll
        for (int rg = 0; rg < 4; ++rg) {
          const int co = m0 + 16 * mi + 4 * s + rg;
          h4s[co * 26 + p] = fmaxf(acc[mi][ni][rg] + b4s[co], 0.0f);
        }
      }
    }
  __syncthreads();

  for (int o = t; o < 600; o += 256) {
    const int fm = o / 25;
    const int p = o - fm * 25;
    float v = b5s[fm];
    const float* wp = &w5s[fm * 128];
    #pragma unroll 8
    for (int ci = 0; ci < 128; ++ci) v = fmaf(wp[ci], h4s[ci * 26 + p], v);
    outs_s[o] = v;
  }
  __syncthreads();

  if (t < 64) {
    float v = (t < 25) ? outs_s[575 + t] : -1e30f;
    #pragma unroll
    for (int off = 32; off; off >>= 1) v = fmaxf(v, __shfl_xor(v, off));
    const float m = v;
    float e = (t < 25) ? expf(outs_s[575 + t] - m) : 0.0f;
    float ss = e;
    #pragma unroll
    for (int off = 32; off; off >>= 1) ss += __shfl_xor(ss, off);
    if (t < 25) att_s[t] = e / ss;
  }
  __syncthreads();

  if (t < 23) {
    float v = 0.f;
    #pragma unroll
    for (int p = 0; p < 25; ++p) v = fmaf(outs_s[t * 25 + p], att_s[p], v);
    pooled[(size_t)(b * KK + k) * 23 + t] = v;
  }
}

// ---------------- pose -> warp templates -> softmax stats ----------------
__device__ inline float tapf(const float* tm, int yi, int xi) {
  const bool ok = (xi >= 0) & (xi < 11) & (yi >= 0) & (yi < 11);
  const int yc = min(max(yi, 0), 10), xc = min(max(xi, 0), 10);
  const float v = tm[yc * 11 + xc];
  return ok ? v : 0.0f;
}

__global__ __launch_bounds__(256) void k_pose_warp(
    const float* __restrict__ pooled, const float* __restrict__ noise,
    const float* __restrict__ templates, float* __restrict__ out,
    float* __restrict__ tt, float* __restrict__ smax, float* __restrict__ sden,
    float* __restrict__ dmw)
{
  const int bk = blockIdx.x;
  const int b = bk / KK;
  const int k = bk - b * KK;
  const int t = threadIdx.x;

  __shared__ float ps[23];
  __shared__ float tm[121];
  __shared__ float red[4];

  if (t < 23) ps[t] = pooled[(size_t)(b * KK + k) * 23 + t];
  for (int i = t; i < 121; i += 256) tm[i] = templates[k * 121 + i];
  __syncthreads();

  float xm[6];
  #pragma unroll
  for (int j = 0; j < 6; ++j) xm[j] = fmaxf(ps[j], 0.0f);
  const float dl = ps[6] + noise[b * KK + k];
  const float dm = 1.0f / (1.0f + expf(-dl));

  const size_t obase = O_OCAE + (size_t)(b * KK + k) * 144;
  if (t < 144) {
    float v;
    if (t == 0)       v = dm;
    else if (t < 7)   v = xm[t - 1];
    else if (t < 128) v = tm[t - 7];
    else              v = fmaxf(ps[7 + (t - 128)], 0.0f);
    out[obase + t] = v;
  }
  if (t < 6) out[O_XM + (size_t)(b * KK + k) * 6 + t] = xm[t];
  if (t == 0) out[O_DM + (b * KK + k)] = dm;

  const float D2R = 0.017453292519943295f;
  const float ang = xm[0] * D2R;
  const float tx = xm[1], ty = xm[2];
  const float sc = xm[3] + 1e-6f;
  const float sxr = xm[4] * D2R, syr = xm[5] * D2R;
  const float cas = cosf(ang - syr), sas = sinf(ang - syr);
  const float csy = cosf(syr), tsx = tanf(sxr);
  const float a_ = cas / csy;
  const float b_ = -cas * tsx / csy - sinf(ang);
  const float c_ = sas / csy;
  const float d_ = -sas * tsx / csy + cosf(ang);
  const float m00 = d_ / sc, m01 = -b_ / sc, m10 = -c_ / sc, m11 = a_ / sc;
  const float m02 = m00 * (-5.0f - tx) + m01 * (-5.0f - ty) + 5.0f;
  const float m12 = m10 * (-5.0f - tx) + m11 * (-5.0f - ty) + 5.0f;

  const float S = 0.275f;
  float ttv[7];
  float lmax = -1e30f;
  #pragma unroll
  for (int i = 0; i < 7; ++i) {
    const int pix = t + 256 * i;
    float val = 0.0f;
    if (pix < 1600) {
      const int py = pix / 40, px = pix - 40 * py;
      const float u = (px + 0.5f) * S - 0.5f;
      const float v = (py + 0.5f) * S - 0.5f;
      const float sx = m00 * u + m01 * v + m02;
      const float sy = m10 * u + m11 * v + m12;
      const float x0 = floorf(sx), y0 = floorf(sy);
      const float wx = sx - x0, wy = sy - y0;
      const int xi = (int)x0, yi = (int)y0;
      const float v00 = tapf(tm, yi, xi);
      const float v01 = tapf(tm, yi, xi + 1);
      const float v10 = tapf(tm, yi + 1, xi);
      const float v11 = tapf(tm, yi + 1, xi + 1);
      val = (v00 * (1.0f - wx) + v01 * wx) * (1.0f - wy) + (v10 * (1.0f - wx) + v11 * wx) * wy;
      tt[(size_t)(b * KK + k) * 1600 + pix] = val;
      lmax = fmaxf(lmax, dm * val);
    }
    ttv[i] = val;
  }

  #pragma unroll
  for (int off = 32; off; off >>= 1) lmax = fmaxf(lmax, __shfl_xor(lmax, off));
  if ((t & 63) == 0) red[t >> 6] = lmax;
  __syncthreads();
  const float m = fmaxf(fmaxf(red[0], red[1]), fmaxf(red[2], red[3]));
  float ls = 0.0f;
  #pragma unroll
  for (int i = 0; i < 7; ++i)
    if (t + 256 * i < 1600) ls += expf(fmaf(dm, ttv[i], -m));
  #pragma unroll
  for (int off = 32; off; off >>= 1) ls += __shfl_xor(ls, off);
  __syncthreads();
  if ((t & 63) == 0) red[t >> 6] = ls;
  __syncthreads();
  if (t == 0) {
    smax[b * KK + k] = m;
    sden[b * KK + k] = red[0] + red[1] + red[2] + red[3];
    dmw[b * KK + k] = dm;
  }
}

// ---------------- per-pixel mixture + log; partial sums ----------------
__global__ __launch_bounds__(256) void k_ll(
    const float* __restrict__ x, const float* __restrict__ tt,
    const float* __restrict__ smax, const float* __restrict__ sden,
    const float* __restrict__ dmw, float* __restrict__ part)
{
  const int b = blockIdx.x >> 2;
  const int chunk = blockIdx.x & 3;
  const int t = threadIdx.x;

  __shared__ __align__(16) float xs[1600];
  __shared__ float kd[24], km[24], ki[24];
  __shared__ float red[4], red2[4];

  for (int i = t; i < 400; i += 256)
    ((float4*)xs)[i] = ((const float4*)(x + (size_t)b * 1600))[i];
  if (t < 24) {
    kd[t] = dmw[b * 24 + t];
    km[t] = smax[b * 24 + t];
    ki[t] = 1.0f / sden[b * 24 + t];
  }
  __syncthreads();

  float s1 = 0.f, s2 = 0.f;
  for (int i = t; i < 1600; i += 256) { const float v = xs[i]; s1 += v; s2 = fmaf(v, v, s2); }
  #pragma unroll
  for (int off = 32; off; off >>= 1) { s1 += __shfl_xor(s1, off); s2 += __shfl_xor(s2, off); }
  if ((t & 63) == 0) { red[t >> 6] = s1; red2[t >> 6] = s2; }
  __syncthreads();
  s1 = red[0] + red[1] + red[2] + red[3];
  s2 = red2[0] + red2[1] + red2[2] + red2[3];
  const float var = (s2 - s1 * s1 * (1.0f / 1600.0f)) * (1.0f / 1599.0f);
  const float stdv = sqrtf(var);
  const float mult = 1.0f / sqrtf(stdv * 6.283185307179586f);
  const float pmul = -1.0f / (2.0f * stdv * stdv);

  const int p0 = chunk * 400;
  float ll = 0.0f;
  for (int ii = t; ii < 400; ii += 256) {
    const int pix = p0 + ii;
    const float xv = xs[pix];
    float sum = 0.0f;
    #pragma unroll 6
    for (int kk2 = 0; kk2 < 24; ++kk2) {
      const float tv = tt[(size_t)(b * 24 + kk2) * 1600 + pix];
      const float dxv = xv - tv;
      sum += expf(fmaf(dxv * dxv, pmul, fmaf(kd[kk2], tv, -km[kk2]))) * ki[kk2];
    }
    ll += logf(mult * sum);
  }
  #pragma unroll
  for (int off = 32; off; off >>= 1) ll += __shfl_xor(ll, off);
  __syncthreads();
  if ((t & 63) == 0) red[t >> 6] = ll;
  __syncthreads();
  if (t == 0) part[blockIdx.x] = red[0] + red[1] + red[2] + red[3];
}

__global__ void k_final(const float* __restrict__ part, float* __restrict__ out)
{
  const int t = threadIdx.x;
  float v = part[t] + part[t + 256];
  #pragma unroll
  for (int off = 32; off; off >>= 1) v += __shfl_xor(v, off);
  __shared__ float red[4];
  if ((t & 63) == 0) red[t >> 6] = v;
  __syncthreads();
  if (t == 0) out[0] = (red[0] + red[1] + red[2] + red[3]) * (1.0f / 128.0f);
}

extern "C" void kernel_launch(void* const* d_in, const int* in_sizes, int n_in,
                              void* d_out, int out_size, void* d_ws, size_t ws_size,
                              hipStream_t stream)
{
  const float* x     = (const float*)d_in[0];
  const float* noise = (const float*)d_in[1];
  const float* W1    = (const float*)d_in[2];
  const float* b1    = (const float*)d_in[3];
  const float* W2    = (const float*)d_in[4];
  const float* b2    = (const float*)d_in[5];
  const float* W3    = (const float*)d_in[6];
  const float* b3    = (const float*)d_in[7];
  const float* W4    = (const float*)d_in[8];
  const float* b4    = (const float*)d_in[9];
  const float* W5    = (const float*)d_in[10];
  const float* b5    = (const float*)d_in[11];
  const float* tmpl  = (const float*)d_in[12];
  float* out = (float*)d_out;
  char* wsb = (char*)d_ws;

  ushort* W1p = (ushort*)(wsb + OFF_W1P);
  ushort* W2p = (ushort*)(wsb + OFF_WB2);
  ushort* W3p = (ushort*)(wsb + OFF_WB3);
  ushort* W4p = (ushort*)(wsb + OFF_WB4);
  ushort* h2T = (ushort*)(wsb + OFF_H2T);
  ushort* h3T = (ushort*)(wsb + OFF_H3T);
  float* poolp = (float*)(wsb + OFF_POOL);
  float* ttp   = (float*)(wsb + OFF_TT);
  float* smaxp = (float*)(wsb + OFF_SMAX);
  float* sdenp = (float*)(wsb + OFF_SDEN);
  float* dmp   = (float*)(wsb + OFF_DM);
  float* partp = (float*)(wsb + OFF_PART);

  k_w1p<<<24, 128, 0, stream>>>(W1, W1p);
  k_wp<<<1152, 256, 0, stream>>>(W2, W3, W4, W2p, W3p, W4p);
  k_conv2m<<<KK * BB, 256, 0, stream>>>(x, W1p, b1, W2p, b2, h2T);
  k_conv3m<<<KK * BB / 2, 256, 0, stream>>>(h2T, W3p, b3, h3T);
  k_conv45m<<<KK * BB, 256, 0, stream>>>(h3T, W4p, b4, W5, b5, poolp);
  k_pose_warp<<<BB * KK, 256, 0, stream>>>(poolp, noise, tmpl, out, ttp, smaxp, sdenp, dmp);
  k_ll<<<BB * 4, 256, 0, stream>>>(x, ttp, smaxp, sdenp, dmp, partp);
  k_final<<<1, 256, 0, stream>>>(partp, out);
}

// Round 6
// 336.004 us; speedup vs baseline: 15.9921x; 1.0391x over previous
//
#include <hip/hip_runtime.h>
#include <math.h>

typedef __attribute__((ext_vector_type(8))) short bf16x8;
typedef __attribute__((ext_vector_type(4))) float f32x4;
typedef unsigned int uint32;
typedef unsigned short ushort;

namespace {
constexpr int KK = 24, BB = 128;

// ---- workspace byte offsets ----
constexpr size_t SZ_W1P = (size_t)24 * 128 * 32 * 2;
constexpr size_t SZ_WB  = (size_t)24 * 128 * 1152 * 2;
constexpr size_t OFF_W1P = 0;
constexpr size_t OFF_WB2 = OFF_W1P + SZ_W1P;
constexpr size_t OFF_WB3 = OFF_WB2 + SZ_WB;
constexpr size_t OFF_WB4 = OFF_WB3 + SZ_WB;
constexpr size_t OFF_TT  = OFF_WB4 + SZ_WB;
constexpr size_t SZ_TT   = (size_t)128 * 24 * 1600 * 4;
constexpr size_t OFF_SMAX = OFF_TT + SZ_TT;
constexpr size_t OFF_SDEN = OFF_SMAX + 12288;
constexpr size_t OFF_DM   = OFF_SDEN + 12288;
constexpr size_t OFF_PART = OFF_DM + 12288;

// ---- output offsets (floats) ----
constexpr long long O_OCAE = 1;
constexpr long long O_XM   = O_OCAE + (long long)BB * KK * 144;
constexpr long long O_DM   = O_XM + (long long)BB * KK * 6;

// ---- R1 phase-aliased LDS region (bytes) ----
constexpr int R1_SZ   = 46256;
constexpr int XIM_OFF = 0;              // ushort [361][24] = 17,328   (conv1 B)
constexpr int H1T_OFF = 17328;          // ushort [361][40] = 28,880 -> 46,208
constexpr int XS_OFF  = R1_SZ - 6400;   // float [1600] (dead after xim build)
constexpr int H2S_OFF = 0;              // ushort [4][81][40] = 25,920
constexpr int H3S_OFF = 25920;          // ushort [4][49][40] = 15,680 -> 41,600
constexpr int H4S_OFF = 0;              // float [128][26] = 13,312
constexpr int W5S_OFF = 13312;          // float [3072] = 12,288 -> 25,600
}

__device__ inline ushort f2bf(float f) {
  uint32 u = __builtin_bit_cast(uint32, f);
  u += 0x7fffu + ((u >> 16) & 1u);
  return (ushort)(u >> 16);
}
__device__ inline uint32 pk2(float a, float b) {
  return (uint32)f2bf(a) | ((uint32)f2bf(b) << 16);
}

// ---------------- weight permutes ----------------
__global__ __launch_bounds__(128) void k_w1p(const float* __restrict__ W1,
                                             ushort* __restrict__ W1p) {
  const int k = blockIdx.x, co = threadIdx.x;
  ushort tmp[32];
  #pragma unroll
  for (int i = 0; i < 32; ++i) tmp[i] = 0;
  #pragma unroll
  for (int j = 0; j < 9; ++j) tmp[j] = f2bf(W1[(k * 128 + co) * 9 + j]);
  uint4* dp = (uint4*)(W1p + ((size_t)k * 128 + co) * 32);
  #pragma unroll
  for (int i = 0; i < 4; ++i) dp[i] = ((uint4*)tmp)[i];
}

__global__ __launch_bounds__(256) void k_wp(
    const float* __restrict__ W2, const float* __restrict__ W3, const float* __restrict__ W4,
    ushort* __restrict__ W2p, ushort* __restrict__ W3p, ushort* __restrict__ W4p) {
  const int blk = blockIdx.x;            // 3*384
  const int sel = blk / 384;
  const int bb = blk - sel * 384;
  const float* src = (sel == 0) ? W2 : (sel == 1) ? W3 : W4;
  ushort* dst = (sel == 0) ? W2p : (sel == 1) ? W3p : W4p;
  const int k = bb >> 4;
  const int co = ((bb & 15) << 3) + (threadIdx.x >> 5);
  const int cil = threadIdx.x & 31;
  #pragma unroll
  for (int c = 0; c < 4; ++c) {
    const float* sp = src + ((size_t)(k * 128 + co) * 128 + c * 32 + cil) * 9;
    float v[9];
    #pragma unroll
    for (int j = 0; j < 9; ++j) v[j] = sp[j];
    ushort* dp = dst + (size_t)(k * 4 + c) * 9 * 128 * 32;
    #pragma unroll
    for (int j = 0; j < 9; ++j) dp[(j * 128 + co) * 32 + cil] = f2bf(v[j]);
  }
}

// ---------------- fused capsule tower: conv1..conv5 + att + pool + pose + warp ----------------
__device__ inline float tapf(const float* tm, int yi, int xi) {
  const bool ok = (xi >= 0) & (xi < 11) & (yi >= 0) & (yi < 11);
  const int yc = min(max(yi, 0), 10), xc = min(max(xi, 0), 10);
  const float v = tm[yc * 11 + xc];
  return ok ? v : 0.0f;
}

__global__ __launch_bounds__(256, 3) void k_tower(
    const float* __restrict__ x, const ushort* __restrict__ W1p, const float* __restrict__ b1,
    const ushort* __restrict__ W2p, const float* __restrict__ b2,
    const ushort* __restrict__ W3p, const float* __restrict__ b3,
    const ushort* __restrict__ W4p, const float* __restrict__ b4,
    const float* __restrict__ W5, const float* __restrict__ b5,
    const float* __restrict__ noise, const float* __restrict__ templates,
    float* __restrict__ out, float* __restrict__ tt,
    float* __restrict__ smax, float* __restrict__ sden, float* __restrict__ dmw)
{
  const int bi = blockIdx.x;
  const int kb = (bi & 7) * 384 + (bi >> 3);   // XCD swizzle: 3 k's per XCD
  const int k = kb >> 7;
  const int b = kb & 127;
  const int t = threadIdx.x;

  __shared__ __align__(16) char R1[R1_SZ];
  __shared__ float b1s[128], b2s[128], b3s[128], b4s[128], b5s[24];
  __shared__ float outs_s[600];
  __shared__ float att_s[25];
  __shared__ float ps[23];
  __shared__ float tm[121];
  __shared__ float red[4];
  __shared__ __align__(16) ushort zlds[8];

  ushort* xim = (ushort*)(R1 + XIM_OFF);
  ushort* h1T = (ushort*)(R1 + H1T_OFF);
  float*  xs  = (float*)(R1 + XS_OFF);
  ushort* h2s = (ushort*)(R1 + H2S_OFF);
  ushort* h3s = (ushort*)(R1 + H3S_OFF);
  float*  h4s = (float*)(R1 + H4S_OFF);
  float*  w5s = (float*)(R1 + W5S_OFF);

  // ---- stage x + biases ----
  for (int i = t; i < 400; i += 256)
    ((float4*)xs)[i] = ((const float4*)(x + (size_t)b * 1600))[i];
  if (t < 128) {
    b1s[t] = b1[k * 128 + t]; b2s[t] = b2[k * 128 + t];
    b3s[t] = b3[k * 128 + t]; b4s[t] = b4[k * 128 + t];
  }
  if (t < 8) zlds[t] = 0;
  __syncthreads();

  // ---- build xim [361][24] from xs (xs dead afterwards) ----
  for (int f = t; f < 361; f += 256) {
    const int py = f / 19, px = f - 19 * py;
    const float* xp = &xs[py * 80 + px * 2];
    uint32 r0 = pk2(xp[0], xp[1]);
    uint32 r1 = pk2(xp[2], xp[40]);
    uint32 r2 = pk2(xp[41], xp[42]);
    uint32 r3 = pk2(xp[80], xp[81]);
    uint32 r4 = (uint32)f2bf(xp[82]);
    uint4* dp = (uint4*)(xim + f * 24);
    dp[0] = make_uint4(r0, r1, r2, r3);
    dp[1] = make_uint4(r4, 0u, 0u, 0u);
    dp[2] = make_uint4(0u, 0u, 0u, 0u);
  }

  const int w = t >> 6, lane = t & 63, r = lane & 15, s = lane >> 4;

  // ================= conv1 + conv2 =================
  {
    const int m0 = (w & 1) * 64;       // conv2: 4 M-tiles
    const int n0 = (w >> 1) * 48;      // conv2: 3 N-tiles
    const int mt = w & 1;              // conv1 M-tile within chunk
    const int nh = w >> 1;
    const int nt0 = nh ? 12 : 0, nt1 = nh ? 23 : 12;

    int pb[3]; bool vld[3];
    #pragma unroll
    for (int ni = 0; ni < 3; ++ni) {
      const int n = n0 + 16 * ni + r;
      const int py = n / 9, px = n - 9 * py;
      pb[ni] = 38 * py + 2 * px;
      vld[ni] = (n < 81);
    }

    f32x4 acc[4][3];
    #pragma unroll
    for (int mi = 0; mi < 4; ++mi)
      #pragma unroll
      for (int ni = 0; ni < 3; ++ni) acc[mi][ni] = (f32x4){0.f, 0.f, 0.f, 0.f};

    for (int c = 0; c < 4; ++c) {
      __syncthreads();   // prev conv2 reads done / xim build done
      // conv1 via MFMA
      {
        const bf16x8 a1 = *(const bf16x8*)(W1p + ((size_t)k * 128 + 32 * c + 16 * mt + r) * 32 + 8 * s);
        for (int nt = nt0; nt < nt1; ++nt) {
          const int n = nt * 16 + r;
          const int pos = (n < 361) ? n : 360;
          const ushort* bp = (s < 2) ? (xim + pos * 24 + 8 * s) : zlds;
          const bf16x8 bv = *(const bf16x8*)bp;
          f32x4 cc = __builtin_amdgcn_mfma_f32_16x16x32_bf16(a1, bv, (f32x4){0.f, 0.f, 0.f, 0.f}, 0, 0, 0);
          if (n < 361) {
            const int cil0 = 16 * mt + 4 * s;
            const float bb0 = b1s[32 * c + cil0], bb1 = b1s[32 * c + cil0 + 1];
            const float bb2 = b1s[32 * c + cil0 + 2], bb3 = b1s[32 * c + cil0 + 3];
            uint2 pk;
            pk.x = pk2(fmaxf(cc[0] + bb0, 0.f), fmaxf(cc[1] + bb1, 0.f));
            pk.y = pk2(fmaxf(cc[2] + bb2, 0.f), fmaxf(cc[3] + bb3, 0.f));
            *(uint2*)(h1T + n * 40 + cil0) = pk;
          }
        }
      }
      __syncthreads();
      // conv2 MFMA, A prefetched from global
      const ushort* Abase = W2p + ((((size_t)k * 4 + c) * 9) * 128 + m0 + r) * 32 + 8 * s;
      bf16x8 Ab[2][4];
      #pragma unroll
      for (int mi = 0; mi < 4; ++mi) Ab[0][mi] = *(const bf16x8*)(Abase + mi * 512);
      #pragma unroll
      for (int j = 0; j < 9; ++j) {
        if (j < 8) {
          #pragma unroll
          for (int mi = 0; mi < 4; ++mi)
            Ab[(j + 1) & 1][mi] = *(const bf16x8*)(Abase + (size_t)(j + 1) * 4096 + mi * 512);
        }
        const int off = (j / 3) * 19 + (j - 3 * (j / 3));
        bf16x8 Bv[3];
        #pragma unroll
        for (int ni = 0; ni < 3; ++ni) {
          const int pos = vld[ni] ? pb[ni] + off : 0;
          Bv[ni] = *(const bf16x8*)(h1T + pos * 40 + 8 * s);
        }
        #pragma unroll
        for (int mi = 0; mi < 4; ++mi)
          #pragma unroll
          for (int ni = 0; ni < 3; ++ni)
            acc[mi][ni] = __builtin_amdgcn_mfma_f32_16x16x32_bf16(Ab[j & 1][mi], Bv[ni], acc[mi][ni], 0, 0, 0);
      }
    }
    __syncthreads();   // all conv2 reads of h1T done; xim dead -> safe to write h2s
    // conv2 epilogue -> h2s [4][81][40]
    #pragma unroll
    for (int mi = 0; mi < 4; ++mi)
      #pragma unroll
      for (int ni = 0; ni < 3; ++ni) {
        const int p = n0 + 16 * ni + r;
        if (p < 81) {
          const int co0 = m0 + 16 * mi + 4 * s;
          const int c2 = co0 >> 5, cil = co0 & 31;
          uint2 pk;
          pk.x = pk2(fmaxf(acc[mi][ni][0] + b2s[co0], 0.f), fmaxf(acc[mi][ni][1] + b2s[co0 + 1], 0.f));
          pk.y = pk2(fmaxf(acc[mi][ni][2] + b2s[co0 + 2], 0.f), fmaxf(acc[mi][ni][3] + b2s[co0 + 3], 0.f));
          *(uint2*)(h2s + (c2 * 81 + p) * 40 + cil) = pk;
        }
      }
  }
  __syncthreads();

  // ================= conv3 =================
  {
    const int m0 = (w & 1) * 64;
    const int n0 = (w >> 1) * 32;
    int pb[2]; bool vld[2];
    #pragma unroll
    for (int ni = 0; ni < 2; ++ni) {
      const int n = n0 + 16 * ni + r;
      const int py = n / 7, px = n - 7 * py;
      pb[ni] = 9 * py + px;
      vld[ni] = (n < 49);
    }
    f32x4 acc[4][2];
    #pragma unroll
    for (int mi = 0; mi < 4; ++mi)
      #pragma unroll
      for (int ni = 0; ni < 2; ++ni) acc[mi][ni] = (f32x4){0.f, 0.f, 0.f, 0.f};

    for (int c = 0; c < 4; ++c) {
      const ushort* Abase = W3p + ((((size_t)k * 4 + c) * 9) * 128 + m0 + r) * 32 + 8 * s;
      bf16x8 Ab[2][4];
      #pragma unroll
      for (int mi = 0; mi < 4; ++mi) Ab[0][mi] = *(const bf16x8*)(Abase + mi * 512);
      #pragma unroll
      for (int j = 0; j < 9; ++j) {
        if (j < 8) {
          #pragma unroll
          for (int mi = 0; mi < 4; ++mi)
            Ab[(j + 1) & 1][mi] = *(const bf16x8*)(Abase + (size_t)(j + 1) * 4096 + mi * 512);
        }
        const int off40 = ((j / 3) * 9 + (j - 3 * (j / 3))) * 40;
        bf16x8 Bv[2];
        #pragma unroll
        for (int ni = 0; ni < 2; ++ni) {
          const int pos40 = (vld[ni] ? pb[ni] : 0) * 40;
          Bv[ni] = *(const bf16x8*)(h2s + c * 3240 + pos40 + off40 + 8 * s);
        }
        #pragma unroll
        for (int mi = 0; mi < 4; ++mi)
          #pragma unroll
          for (int ni = 0; ni < 2; ++ni)
            acc[mi][ni] = __builtin_amdgcn_mfma_f32_16x16x32_bf16(Ab[j & 1][mi], Bv[ni], acc[mi][ni], 0, 0, 0);
      }
    }
    __syncthreads();   // all h2s reads done -> safe to overwrite (w5s) & write h3s
    // conv3 epilogue -> h3s [4][49][40]; stage W5/b5 into freed h2s region
    #pragma unroll
    for (int mi = 0; mi < 4; ++mi)
      #pragma unroll
      for (int ni = 0; ni < 2; ++ni) {
        const int p = n0 + 16 * ni + r;
        if (p < 49) {
          const int co0 = m0 + 16 * mi + 4 * s;
          const int c2 = co0 >> 5, cil = co0 & 31;
          uint2 pk;
          pk.x = pk2(fmaxf(acc[mi][ni][0] + b3s[co0], 0.f), fmaxf(acc[mi][ni][1] + b3s[co0 + 1], 0.f));
          pk.y = pk2(fmaxf(acc[mi][ni][2] + b3s[co0 + 2], 0.f), fmaxf(acc[mi][ni][3] + b3s[co0 + 3], 0.f));
          *(uint2*)(h3s + (c2 * 49 + p) * 40 + cil) = pk;
        }
      }
    for (int i = t; i < 3072; i += 256) w5s[i] = W5[k * 3072 + i];
    if (t < 24) b5s[t] = b5[k * 24 + t];
    for (int i = t; i < 121; i += 256) tm[i] = templates[k * 121 + i];
  }
  __syncthreads();

  // ================= conv4 =================
  {
    const int m0 = w * 32;
    int base[2];
    #pragma unroll
    for (int ni = 0; ni < 2; ++ni) {
      const int n = 16 * ni + r;
      const int py = n / 5, px = n - 5 * py;
      base[ni] = ((n < 25) ? (7 * py + px) : 0) * 40 + 8 * s;
    }
    f32x4 acc[2][2];
    #pragma unroll
    for (int mi = 0; mi < 2; ++mi)
      #pragma unroll
      for (int ni = 0; ni < 2; ++ni) acc[mi][ni] = (f32x4){0.f, 0.f, 0.f, 0.f};

    for (int c = 0; c < 4; ++c) {
      const ushort* Abase = W4p + ((((size_t)k * 4 + c) * 9) * 128 + m0 + r) * 32 + 8 * s;
      bf16x8 Ab[2][2];
      #pragma unroll
      for (int mi = 0; mi < 2; ++mi) Ab[0][mi] = *(const bf16x8*)(Abase + mi * 512);
      #pragma unroll
      for (int j = 0; j < 9; ++j) {
        if (j < 8) {
          #pragma unroll
          for (int mi = 0; mi < 2; ++mi)
            Ab[(j + 1) & 1][mi] = *(const bf16x8*)(Abase + (size_t)(j + 1) * 4096 + mi * 512);
        }
        const int off40 = ((j / 3) * 7 + (j - 3 * (j / 3))) * 40;
        bf16x8 Bv[2];
        #pragma unroll
        for (int ni = 0; ni < 2; ++ni)
          Bv[ni] = *(const bf16x8*)(h3s + c * 1960 + base[ni] + off40);
        #pragma unroll
        for (int mi = 0; mi < 2; ++mi)
          #pragma unroll
          for (int ni = 0; ni < 2; ++ni)
            acc[mi][ni] = __builtin_amdgcn_mfma_f32_16x16x32_bf16(Ab[j & 1][mi], Bv[ni], acc[mi][ni], 0, 0, 0);
      }
    }
    __syncthreads();   // h3s reads done; h4s region (old h2s[0:13312)) free
    #pragma unroll
    for (int mi = 0; mi < 2; ++mi)
      #pragma unroll
      for (int ni = 0; ni < 2; ++ni) {
        const int p = 16 * ni + r;
        if (p < 25) {
          #pragma unroll
          for (int rg = 0; rg < 4; ++rg) {
            const int co = m0 + 16 * mi + 4 * s + rg;
            h4s[co * 26 + p] = fmaxf(acc[mi][ni][rg] + b4s[co], 0.0f);
          }
        }
      }
  }
  __syncthreads();

  // ================= conv5 + att softmax + pool =================
  for (int o = t; o < 600; o += 256) {
    const int fm = o / 25;
    const int p = o - fm * 25;
    float v = b5s[fm];
    const float* wp = &w5s[fm * 128];
    #pragma unroll 8
    for (int ci = 0; ci < 128; ++ci) v = fmaf(wp[ci], h4s[ci * 26 + p], v);
    outs_s[o] = v;
  }
  __syncthreads();

  if (t < 64) {
    float v = (t < 25) ? outs_s[575 + t] : -1e30f;
    #pragma unroll
    for (int off = 32; off; off >>= 1) v = fmaxf(v, __shfl_xor(v, off));
    const float m = v;
    float e = (t < 25) ? expf(outs_s[575 + t] - m) : 0.0f;
    float ss = e;
    #pragma unroll
    for (int off = 32; off; off >>= 1) ss += __shfl_xor(ss, off);
    if (t < 25) att_s[t] = e / ss;
  }
  __syncthreads();

  if (t < 23) {
    float v = 0.f;
    #pragma unroll
    for (int p = 0; p < 25; ++p) v = fmaf(outs_s[t * 25 + p], att_s[p], v);
    ps[t] = v;
  }
  __syncthreads();

  // ================= pose + warp + softmax stats =================
  const int idx = b * KK + k;
  float xm[6];
  #pragma unroll
  for (int j = 0; j < 6; ++j) xm[j] = fmaxf(ps[j], 0.0f);
  const float dl = ps[6] + noise[idx];
  const float dm = 1.0f / (1.0f + expf(-dl));

  const size_t obase = O_OCAE + (size_t)idx * 144;
  if (t < 144) {
    float v;
    if (t == 0)       v = dm;
    else if (t < 7)   v = xm[t - 1];
    else if (t < 128) v = tm[t - 7];
    else              v = fmaxf(ps[7 + (t - 128)], 0.0f);
    out[obase + t] = v;
  }
  if (t < 6) out[O_XM + (size_t)idx * 6 + t] = xm[t];
  if (t == 0) out[O_DM + idx] = dm;

  const float D2R = 0.017453292519943295f;
  const float ang = xm[0] * D2R;
  const float tx = xm[1], ty = xm[2];
  const float sc = xm[3] + 1e-6f;
  const float sxr = xm[4] * D2R, syr = xm[5] * D2R;
  const float cas = cosf(ang - syr), sas = sinf(ang - syr);
  const float csy = cosf(syr), tsx = tanf(sxr);
  const float a_ = cas / csy;
  const float b_ = -cas * tsx / csy - sinf(ang);
  const float c_ = sas / csy;
  const float d_ = -sas * tsx / csy + cosf(ang);
  const float m00 = d_ / sc, m01 = -b_ / sc, m10 = -c_ / sc, m11 = a_ / sc;
  const float m02 = m00 * (-5.0f - tx) + m01 * (-5.0f - ty) + 5.0f;
  const float m12 = m10 * (-5.0f - tx) + m11 * (-5.0f - ty) + 5.0f;

  const float S = 0.275f;
  float ttv[7];
  float lmax = -1e30f;
  #pragma unroll
  for (int i = 0; i < 7; ++i) {
    const int pix = t + 256 * i;
    float val = 0.0f;
    if (pix < 1600) {
      const int py = pix / 40, px = pix - 40 * py;
      const float u = (px + 0.5f) * S - 0.5f;
      const float v = (py + 0.5f) * S - 0.5f;
      const float sx = m00 * u + m01 * v + m02;
      const float sy = m10 * u + m11 * v + m12;
      const float x0 = floorf(sx), y0 = floorf(sy);
      const float wx = sx - x0, wy = sy - y0;
      const int xi = (int)x0, yi = (int)y0;
      const float v00 = tapf(tm, yi, xi);
      const float v01 = tapf(tm, yi, xi + 1);
      const float v10 = tapf(tm, yi + 1, xi);
      const float v11 = tapf(tm, yi + 1, xi + 1);
      val = (v00 * (1.0f - wx) + v01 * wx) * (1.0f - wy) + (v10 * (1.0f - wx) + v11 * wx) * wy;
      tt[(size_t)idx * 1600 + pix] = val;
      lmax = fmaxf(lmax, dm * val);
    }
    ttv[i] = val;
  }

  #pragma unroll
  for (int off = 32; off; off >>= 1) lmax = fmaxf(lmax, __shfl_xor(lmax, off));
  if ((t & 63) == 0) red[t >> 6] = lmax;
  __syncthreads();
  const float m = fmaxf(fmaxf(red[0], red[1]), fmaxf(red[2], red[3]));
  float ls = 0.0f;
  #pragma unroll
  for (int i = 0; i < 7; ++i)
    if (t + 256 * i < 1600) ls += expf(fmaf(dm, ttv[i], -m));
  #pragma unroll
  for (int off = 32; off; off >>= 1) ls += __shfl_xor(ls, off);
  __syncthreads();
  if ((t & 63) == 0) red[t >> 6] = ls;
  __syncthreads();
  if (t == 0) {
    smax[idx] = m;
    sden[idx] = red[0] + red[1] + red[2] + red[3];
    dmw[idx] = dm;
  }
}

// ---------------- per-pixel mixture + log; partial sums ----------------
__global__ __launch_bounds__(256) void k_ll(
    const float* __restrict__ x, const float* __restrict__ tt,
    const float* __restrict__ smax, const float* __restrict__ sden,
    const float* __restrict__ dmw, float* __restrict__ part)
{
  const int b = blockIdx.x >> 2;
  const int chunk = blockIdx.x & 3;
  const int t = threadIdx.x;

  __shared__ __align__(16) float xs[1600];
  __shared__ float kd[24], km[24], ki[24];
  __shared__ float red[4], red2[4];

  for (int i = t; i < 400; i += 256)
    ((float4*)xs)[i] = ((const float4*)(x + (size_t)b * 1600))[i];
  if (t < 24) {
    kd[t] = dmw[b * 24 + t];
    km[t] = smax[b * 24 + t];
    ki[t] = 1.0f / sden[b * 24 + t];
  }
  __syncthreads();

  float s1 = 0.f, s2 = 0.f;
  for (int i = t; i < 1600; i += 256) { const float v = xs[i]; s1 += v; s2 = fmaf(v, v, s2); }
  #pragma unroll
  for (int off = 32; off; off >>= 1) { s1 += __shfl_xor(s1, off); s2 += __shfl_xor(s2, off); }
  if ((t & 63) == 0) { red[t >> 6] = s1; red2[t >> 6] = s2; }
  __syncthreads();
  s1 = red[0] + red[1] + red[2] + red[3];
  s2 = red2[0] + red2[1] + red2[2] + red2[3];
  const float var = (s2 - s1 * s1 * (1.0f / 1600.0f)) * (1.0f / 1599.0f);
  const float stdv = sqrtf(var);
  const float mult = 1.0f / sqrtf(stdv * 6.283185307179586f);
  const float pmul = -1.0f / (2.0f * stdv * stdv);

  const int p0 = chunk * 400;
  float ll = 0.0f;
  for (int ii = t; ii < 400; ii += 256) {
    const int pix = p0 + ii;
    const float xv = xs[pix];
    float sum = 0.0f;
    #pragma unroll 6
    for (int kk2 = 0; kk2 < 24; ++kk2) {
      const float tv = tt[(size_t)(b * 24 + kk2) * 1600 + pix];
      const float dxv = xv - tv;
      sum += expf(fmaf(dxv * dxv, pmul, fmaf(kd[kk2], tv, -km[kk2]))) * ki[kk2];
    }
    ll += logf(mult * sum);
  }
  #pragma unroll
  for (int off = 32; off; off >>= 1) ll += __shfl_xor(ll, off);
  __syncthreads();
  if ((t & 63) == 0) red[t >> 6] = ll;
  __syncthreads();
  if (t == 0) part[blockIdx.x] = red[0] + red[1] + red[2] + red[3];
}

__global__ void k_final(const float* __restrict__ part, float* __restrict__ out)
{
  const int t = threadIdx.x;
  float v = part[t] + part[t + 256];
  #pragma unroll
  for (int off = 32; off; off >>= 1) v += __shfl_xor(v, off);
  __shared__ float red[4];
  if ((t & 63) == 0) red[t >> 6] = v;
  __syncthreads();
  if (t == 0) out[0] = (red[0] + red[1] + red[2] + red[3]) * (1.0f / 128.0f);
}

extern "C" void kernel_launch(void* const* d_in, const int* in_sizes, int n_in,
                              void* d_out, int out_size, void* d_ws, size_t ws_size,
                              hipStream_t stream)
{
  const float* x     = (const float*)d_in[0];
  const float* noise = (const float*)d_in[1];
  const float* W1    = (const float*)d_in[2];
  const float* b1    = (const float*)d_in[3];
  const float* W2    = (const float*)d_in[4];
  const float* b2    = (const float*)d_in[5];
  const float* W3    = (const float*)d_in[6];
  const float* b3    = (const float*)d_in[7];
  const float* W4    = (const float*)d_in[8];
  const float* b4    = (const float*)d_in[9];
  const float* W5    = (const float*)d_in[10];
  const float* b5    = (const float*)d_in[11];
  const float* tmpl  = (const float*)d_in[12];
  float* out = (float*)d_out;
  char* wsb = (char*)d_ws;

  ushort* W1p = (ushort*)(wsb + OFF_W1P);
  ushort* W2p = (ushort*)(wsb + OFF_WB2);
  ushort* W3p = (ushort*)(wsb + OFF_WB3);
  ushort* W4p = (ushort*)(wsb + OFF_WB4);
  float* ttp   = (float*)(wsb + OFF_TT);
  float* smaxp = (float*)(wsb + OFF_SMAX);
  float* sdenp = (float*)(wsb + OFF_SDEN);
  float* dmp   = (float*)(wsb + OFF_DM);
  float* partp = (float*)(wsb + OFF_PART);

  k_w1p<<<24, 128, 0, stream>>>(W1, W1p);
  k_wp<<<1152, 256, 0, stream>>>(W2, W3, W4, W2p, W3p, W4p);
  k_tower<<<KK * BB, 256, 0, stream>>>(x, W1p, b1, W2p, b2, W3p, b3, W4p, b4,
                                       W5, b5, noise, tmpl, out, ttp, smaxp, sdenp, dmp);
  k_ll<<<BB * 4, 256, 0, stream>>>(x, ttp, smaxp, sdenp, dmp, partp);
  k_final<<<1, 256, 0, stream>>>(partp, out);
}